// Round 4
// baseline (1566.406 us; speedup 1.0000x reference)
//
#include <hip/hip_runtime.h>
#include <math.h>

#define TT 1024
#define DD 384
#define NH 6
#define DI 768
#define MH 12
#define DS 64
#define NL 8
#define XDIM 1676   // 2*DI + 2*DS + MH
#define CONVC 896   // DI + 2*DS
#define NV 32000
#define PW 1920     // fused projection width: [r|k|v|g|w] * 384
#define CHK 64      // scan chunk length
#define NCH 16      // number of chunks

typedef __attribute__((ext_vector_type(8))) short short8;
typedef __attribute__((ext_vector_type(4))) float f32x4;

// ---------------- helpers ----------------
__device__ __forceinline__ float siluf(float x) { return x / (1.f + expf(-x)); }
__device__ __forceinline__ float sigmoidf_(float x) { return 1.f / (1.f + expf(-x)); }
__device__ __forceinline__ float geluf(float x) {
  return 0.5f * x * (1.f + erff(x * 0.70710678118654752440f));
}
__device__ __forceinline__ unsigned short f2b(float x) {
  union { float f; unsigned int u; } v; v.f = x;
  unsigned int r = v.u + 0x7fffu + ((v.u >> 16) & 1u);
  return (unsigned short)(r >> 16);
}

#define GLDS(gp, lp) __builtin_amdgcn_global_load_lds( \
    (const __attribute__((address_space(1))) void*)(gp), \
    (__attribute__((address_space(3))) void*)(lp), 16, 0, 0)

// ---------------- 64-tile bf16 MFMA GEMM. EPI: 0=store f32, 2=add-residual ----------------
template<int EPI>
__global__ __launch_bounds__(256) void gemm_bf16(
    const unsigned short* __restrict__ A, const unsigned short* __restrict__ Bt,
    float* __restrict__ C, int N, int K, int ldC)
{
  __shared__ unsigned short As[2048];   // [64][32]
  __shared__ unsigned short Bs[2048];
  int tid = threadIdx.x;
  int wid = tid >> 6, lane = tid & 63;
  int m0 = blockIdx.y * 64, n0 = blockIdx.x * 64;
  int wr = wid >> 1, wc = wid & 1;
  int sr = tid >> 2;
  int scs = ((tid & 3) ^ ((sr >> 1) & 3)) * 8;
  const unsigned short* ga = A  + (size_t)(m0 + sr) * K + scs;
  const unsigned short* gb = Bt + (size_t)(n0 + sr) * K + scs;
  unsigned short* la = As + wid * 512;
  unsigned short* lb = Bs + wid * 512;
  int fr = lane & 15, fc = lane >> 4;
  f32x4 zz = {0.f, 0.f, 0.f, 0.f};
  f32x4 acc[2][2];
  acc[0][0] = zz; acc[0][1] = zz; acc[1][0] = zz; acc[1][1] = zz;

  for (int k0 = 0; k0 < K; k0 += 32) {
    GLDS(ga + k0, la);
    GLDS(gb + k0, lb);
    __syncthreads();
    short8 af[2], bf[2];
#pragma unroll
    for (int mg = 0; mg < 2; ++mg) {
      int ar = wr * 32 + mg * 16 + fr;
      af[mg] = *reinterpret_cast<const short8*>(&As[ar * 32 + ((fc ^ ((ar >> 1) & 3)) * 8)]);
    }
#pragma unroll
    for (int ng = 0; ng < 2; ++ng) {
      int br = wc * 32 + ng * 16 + fr;
      bf[ng] = *reinterpret_cast<const short8*>(&Bs[br * 32 + ((fc ^ ((br >> 1) & 3)) * 8)]);
    }
#pragma unroll
    for (int mg = 0; mg < 2; ++mg)
#pragma unroll
      for (int ng = 0; ng < 2; ++ng)
        acc[mg][ng] = __builtin_amdgcn_mfma_f32_16x16x32_bf16(af[mg], bf[ng], acc[mg][ng], 0, 0, 0);
    __syncthreads();
  }
#pragma unroll
  for (int mg = 0; mg < 2; ++mg)
#pragma unroll
    for (int ng = 0; ng < 2; ++ng) {
      int col = n0 + wc * 32 + ng * 16 + fr;
      if (col < N) {
#pragma unroll
        for (int j = 0; j < 4; ++j) {
          int row = m0 + wr * 32 + mg * 16 + fc * 4 + j;
          if (EPI == 2) C[(size_t)row * ldC + col] += acc[mg][ng][j];
          else          C[(size_t)row * ldC + col]  = acc[mg][ng][j];
        }
      }
    }
}

// ---------------- 128-tile bf16 MFMA GEMM. EPI: 0=store f32, 1=gelu->bf16 ----------------
template<int EPI>
__global__ __launch_bounds__(256) void gemm128(
    const unsigned short* __restrict__ A, const unsigned short* __restrict__ Bt,
    float* __restrict__ C, unsigned short* __restrict__ Cb, int N, int K, int ldC)
{
  __shared__ unsigned short As[4096];   // [128][32] (chunk-linear)
  __shared__ unsigned short Bs[4096];
  int tid = threadIdx.x;
  int wid = tid >> 6, lane = tid & 63;
  int m0 = blockIdx.y * 128, n0 = blockIdx.x * 128;
  int wr = wid >> 1, wc = wid & 1;
  int r0 = tid >> 2;
  int scs = ((tid & 3) ^ ((r0 >> 1) & 3)) * 8;
  const unsigned short* ga0 = A  + (size_t)(m0 + r0) * K + scs;
  const unsigned short* gb0 = Bt + (size_t)(n0 + r0) * K + scs;
  const unsigned short* ga1 = ga0 + (size_t)64 * K;   // rows +64: same swizzle (pair idx +32 == mod 4)
  const unsigned short* gb1 = gb0 + (size_t)64 * K;
  unsigned short* la0 = As + wid * 512;
  unsigned short* lb0 = Bs + wid * 512;
  unsigned short* la1 = As + 2048 + wid * 512;
  unsigned short* lb1 = Bs + 2048 + wid * 512;
  int fr = lane & 15, fc = lane >> 4;
  f32x4 zz = {0.f, 0.f, 0.f, 0.f};
  f32x4 acc[4][4];
#pragma unroll
  for (int i = 0; i < 4; i++)
#pragma unroll
    for (int j = 0; j < 4; j++) acc[i][j] = zz;

  for (int k0 = 0; k0 < K; k0 += 32) {
    GLDS(ga0 + k0, la0);
    GLDS(gb0 + k0, lb0);
    GLDS(ga1 + k0, la1);
    GLDS(gb1 + k0, lb1);
    __syncthreads();
    short8 af[4], bf[4];
#pragma unroll
    for (int mg = 0; mg < 4; ++mg) {
      int ar = wr * 64 + mg * 16 + fr;
      af[mg] = *reinterpret_cast<const short8*>(&As[ar * 32 + ((fc ^ ((ar >> 1) & 3)) * 8)]);
    }
#pragma unroll
    for (int ng = 0; ng < 4; ++ng) {
      int br = wc * 64 + ng * 16 + fr;
      bf[ng] = *reinterpret_cast<const short8*>(&Bs[br * 32 + ((fc ^ ((br >> 1) & 3)) * 8)]);
    }
#pragma unroll
    for (int mg = 0; mg < 4; ++mg)
#pragma unroll
      for (int ng = 0; ng < 4; ++ng)
        acc[mg][ng] = __builtin_amdgcn_mfma_f32_16x16x32_bf16(af[mg], bf[ng], acc[mg][ng], 0, 0, 0);
    __syncthreads();
  }
#pragma unroll
  for (int mg = 0; mg < 4; ++mg)
#pragma unroll
    for (int ng = 0; ng < 4; ++ng) {
      int col = n0 + wc * 64 + ng * 16 + fr;
      if (col < N) {
#pragma unroll
        for (int j = 0; j < 4; ++j) {
          int row = m0 + wr * 64 + mg * 16 + fc * 4 + j;
          if (EPI == 1) Cb[(size_t)row * ldC + col] = f2b(geluf(acc[mg][ng][j]));
          else          C [(size_t)row * ldC + col] = acc[mg][ng][j];
        }
      }
    }
}

// ---------------- weight transpose + fp32->bf16 ----------------
__global__ __launch_bounds__(256) void transconv_kernel(
    const float* __restrict__ src, unsigned short* __restrict__ dst,
    int K, int N, int Npad, size_t srcStride, size_t dstStride)
{
  __shared__ float tile[32][33];
  src += (size_t)blockIdx.z * srcStride;
  dst += (size_t)blockIdx.z * dstStride;
  int k0 = blockIdx.y * 32, n0 = blockIdx.x * 32;
  int tx = threadIdx.x & 31, ty = threadIdx.x >> 5;
  for (int i = ty; i < 32; i += 8) {
    int k = k0 + i, n = n0 + tx;
    tile[i][tx] = (k < K && n < N) ? src[(size_t)k * N + n] : 0.f;
  }
  __syncthreads();
  for (int i = ty; i < 32; i += 8) {
    int n = n0 + i, k = k0 + tx;
    if (n < Npad && k < K) dst[(size_t)n * K + k] = f2b(tile[tx][i]);
  }
}

__global__ void conv_b16_kernel(const float* __restrict__ src, unsigned short* __restrict__ dst, int n)
{
  int idx = blockIdx.x * 256 + threadIdx.x;
  if (idx < n) dst[idx] = f2b(src[idx]);
}

// ---------------- embedding gather ----------------
__global__ void embed_kernel(const int* __restrict__ x, const float* __restrict__ embed,
                             float* __restrict__ h)
{
  int idx = blockIdx.x * 256 + threadIdx.x;
  if (idx < TT * DD) {
    int t = idx / DD, d = idx % DD;
    h[idx] = embed[(size_t)x[t] * DD + d];
  }
}

// ---------------- RMSNorm -> bf16 out ----------------
__global__ __launch_bounds__(256) void rms_kernel(const float* __restrict__ in,
                                                  const float* __restrict__ w,
                                                  unsigned short* __restrict__ out,
                                                  int ncol, float eps)
{
  int t = blockIdx.x;
  const float* row = in + (size_t)t * ncol;
  float ss = 0.f;
  for (int c = threadIdx.x; c < ncol; c += 256) { float v = row[c]; ss = fmaf(v, v, ss); }
  __shared__ float red[256];
  red[threadIdx.x] = ss; __syncthreads();
  for (int s = 128; s > 0; s >>= 1) {
    if (threadIdx.x < s) red[threadIdx.x] += red[threadIdx.x + s];
    __syncthreads();
  }
  float scale = rsqrtf(red[0] / ncol + eps);
  for (int c = threadIdx.x; c < ncol; c += 256) out[(size_t)t * ncol + c] = f2b(w[c] * row[c] * scale);
}

// ---------------- Phase A: per-chunk local scans (decay & dt fused) ----------------
// blocks 0..95: RWKV (h = b>>4, chunk c = b&15); 96..287: Mamba (hh, c)
__global__ __launch_bounds__(256) void scanA_kernel(
    const float* __restrict__ P, const float* __restrict__ u, const float* __restrict__ wbias,
    float* __restrict__ so, float* __restrict__ rPb,
    float* __restrict__ MstR, float* __restrict__ DcR,
    const float* __restrict__ xbc, const float* __restrict__ zx, const float* __restrict__ dtbias,
    const float* __restrict__ Alog, const float* __restrict__ Dpw,
    float* __restrict__ yb, float* __restrict__ Ccb,
    float* __restrict__ MstM, float* __restrict__ DcM)
{
  __shared__ float smem[2 * 256 + 64];
  int b = blockIdx.x, tid = threadIdx.x;
  if (b < 96) {
    int h = b >> 4, c = b & 15;
    float* sbuf = smem; float* us = smem + 512;
    if (tid < 64) us[tid] = u[h * 64 + tid];
    int wv = tid >> 6, l = tid & 63;
    int vv = wv * 16 + (l & 15);
    int kc = l >> 4;
    int arr = tid >> 6, idx = tid & 63;
    int off = (arr == 0) ? 0 : (arr == 1) ? 384 : (arr == 2) ? 1536 : 768;  // r,k,w(raw),v
    float wb = (arr == 2) ? wbias[h * 64 + idx] : 0.f;
    size_t base = (size_t)h * 64 + idx + off;
    int t0 = c * CHK;
    float S[16], Pc[16];
#pragma unroll
    for (int i = 0; i < 16; i++) { S[i] = 0.f; Pc[i] = 1.f; }
    float reg = P[(size_t)t0 * PW + base];
    bool st = (wv == 0) && ((l & 15) == 0);   // 4 threads, kc = 0..3
    for (int t = 0; t < CHK; ++t) {
      int tt = t0 + t;
      float* cb = sbuf + (t & 1) * 256;
      cb[arr * 64 + idx] = (arr == 2) ? expf(-expf(reg + wb)) : reg;
      if (t + 1 < CHK) reg = P[(size_t)(tt + 1) * PW + base];
      __syncthreads();
      float vt = cb[192 + vv];
      float acc = 0.f;
      float rp[16];
#pragma unroll
      for (int i = 0; i < 16; ++i) {
        int kk = kc * 16 + i;
        float rv = cb[kk], kv = cb[64 + kk], dv = cb[128 + kk];
        rp[i] = rv * Pc[i];
        float kvv = kv * vt;
        acc = fmaf(rv, fmaf(us[kk], kvv, S[i]), acc);
        S[i] = fmaf(dv, S[i], kvv);
        Pc[i] *= dv;
      }
      acc += __shfl_xor(acc, 16);
      acc += __shfl_xor(acc, 32);
      if (l < 16) so[(size_t)tt * DD + h * 64 + vv] = acc;
      if (st) {
        float4* dst = (float4*)&rPb[(size_t)tt * DD + h * 64 + kc * 16];
        dst[0] = make_float4(rp[0], rp[1], rp[2], rp[3]);
        dst[1] = make_float4(rp[4], rp[5], rp[6], rp[7]);
        dst[2] = make_float4(rp[8], rp[9], rp[10], rp[11]);
        dst[3] = make_float4(rp[12], rp[13], rp[14], rp[15]);
      }
    }
    float* ms = MstR + (size_t)(h * NCH + c) * 4096;   // [v][k]
    float4* msv = (float4*)&ms[vv * 64 + kc * 16];
    msv[0] = make_float4(S[0], S[1], S[2], S[3]);
    msv[1] = make_float4(S[4], S[5], S[6], S[7]);
    msv[2] = make_float4(S[8], S[9], S[10], S[11]);
    msv[3] = make_float4(S[12], S[13], S[14], S[15]);
    if (st) {
      float4* dd_ = (float4*)&DcR[(h * NCH + c) * 64 + kc * 16];
      dd_[0] = make_float4(Pc[0], Pc[1], Pc[2], Pc[3]);
      dd_[1] = make_float4(Pc[4], Pc[5], Pc[6], Pc[7]);
      dd_[2] = make_float4(Pc[8], Pc[9], Pc[10], Pc[11]);
      dd_[3] = make_float4(Pc[12], Pc[13], Pc[14], Pc[15]);
    }
  } else {
    int bb = b - 96;
    int hh = bb >> 4, c = bb & 15;
    float* sbuf = smem;
    int wv = tid >> 6, l = tid & 63;
    int p = wv * 16 + (l & 15);
    int sc = l >> 4;
    int arr = tid >> 6, idx = tid & 63;
    float A = -expf(Alog[hh]);
    float Dph = Dpw[hh];
    float dtbh = dtbias[hh];
    int off = (arr == 0) ? (hh * 64 + idx) : (arr == 1) ? (DI + idx) : (DI + DS + idx);
    int t0 = c * CHK;
    float S[16]; float cdA = 1.f;
#pragma unroll
    for (int i = 0; i < 16; i++) S[i] = 0.f;
    float reg = (arr < 3) ? xbc[(size_t)t0 * CONVC + off]
                          : zx[(size_t)t0 * XDIM + (XDIM - MH) + hh];
    bool st = (wv == 0) && ((l & 15) == 0);
    for (int t = 0; t < CHK; ++t) {
      int tt = t0 + t;
      float* cb = sbuf + (t & 1) * 256;
      if (arr < 3) cb[arr * 64 + idx] = reg;
      else if (idx == 0) {
        float v = reg + dtbh;
        cb[192] = (v > 20.f) ? v : log1pf(expf(v));
      }
      if (t + 1 < CHK) reg = (arr < 3) ? xbc[(size_t)(tt + 1) * CONVC + off]
                                       : zx[(size_t)(tt + 1) * XDIM + (XDIM - MH) + hh];
      __syncthreads();
      float dt_ = cb[192];
      float dA = expf(dt_ * A);
      cdA *= dA;
      float xp = cb[p];
      float dtx = dt_ * xp;
      float acc = 0.f;
#pragma unroll
      for (int i = 0; i < 16; ++i) {
        int s = sc * 16 + i;
        S[i] = fmaf(dA, S[i], dtx * cb[64 + s]);
        acc = fmaf(S[i], cb[128 + s], acc);
      }
      acc += __shfl_xor(acc, 16);
      acc += __shfl_xor(acc, 32);
      if (l < 16) yb[(size_t)tt * DI + hh * 64 + p] = fmaf(Dph, xp, acc);
      if (st) {
        float4* dst = (float4*)&Ccb[(size_t)tt * DI + hh * 64 + sc * 16];
#pragma unroll
        for (int j4 = 0; j4 < 4; ++j4)
          dst[j4] = make_float4(cdA * cb[128 + sc * 16 + j4 * 4 + 0],
                                cdA * cb[128 + sc * 16 + j4 * 4 + 1],
                                cdA * cb[128 + sc * 16 + j4 * 4 + 2],
                                cdA * cb[128 + sc * 16 + j4 * 4 + 3]);
      }
    }
    float* ms = MstM + (size_t)(hh * NCH + c) * 4096;  // [p][s]
    float4* msv = (float4*)&ms[p * 64 + sc * 16];
    msv[0] = make_float4(S[0], S[1], S[2], S[3]);
    msv[1] = make_float4(S[4], S[5], S[6], S[7]);
    msv[2] = make_float4(S[8], S[9], S[10], S[11]);
    msv[3] = make_float4(S[12], S[13], S[14], S[15]);
    if (tid == 0) DcM[hh * NCH + c] = cdA;
  }
}

// ---------------- Phase B: chunk-state combine ----------------
__global__ __launch_bounds__(256) void combine_kernel(
    const float* __restrict__ MstR, const float* __restrict__ DcR, float* __restrict__ S0R,
    const float* __restrict__ MstM, const float* __restrict__ DcM, float* __restrict__ S0M)
{
  int b = blockIdx.x, tid = threadIdx.x;
  if (b < 96) {
    int h = b >> 4, sub = b & 15;
    int ei = sub * 256 + tid;         // element in [v][k]
    int k = ei & 63;
    float S = 0.f;
#pragma unroll
    for (int c = 0; c < NCH; ++c) {
      size_t base = (size_t)(h * NCH + c) * 4096;
      float m = MstR[base + ei];
      float dD = DcR[(h * NCH + c) * 64 + k];
      S0R[base + ei] = S;
      S = fmaf(dD, S, m);
    }
  } else {
    int bb = b - 96;
    int hh = bb >> 4, sub = bb & 15;
    int ei = sub * 256 + tid;
    float S = 0.f;
#pragma unroll
    for (int c = 0; c < NCH; ++c) {
      size_t base = (size_t)(hh * NCH + c) * 4096;
      float m = MstM[base + ei];
      float dD = DcM[hh * NCH + c];
      S0M[base + ei] = S;
      S = fmaf(dD, S, m);
    }
  }
}

// ---------------- Phase C: output correction (+ fused RWKV groupnorm*silu for b<96) ----------------
__global__ __launch_bounds__(256) void corr_kernel(
    const float* __restrict__ S0R, const float* __restrict__ rPb, const float* __restrict__ so,
    const float* __restrict__ S0M, const float* __restrict__ Ccb, float* __restrict__ yb,
    const float* __restrict__ P, const float* __restrict__ gnw, const float* __restrict__ gnb,
    unsigned short* __restrict__ gob)
{
  __shared__ float S0l[64 * 68];
  __shared__ float Rl[64 * 68];
  int b = blockIdx.x, tid = threadIdx.x;
  const float* s0g; const float* rg; int ostride, obase, t0;
  bool rwkv = (b < 96);
  int h;
  if (rwkv) {
    h = b >> 4; int c = b & 15; t0 = c * CHK;
    s0g = S0R + (size_t)(h * NCH + c) * 4096;   // [v][k]
    rg = rPb; obase = h * 64; ostride = DD;
  } else {
    int bb = b - 96; h = bb >> 4; int c = bb & 15; t0 = c * CHK;
    s0g = S0M + (size_t)(h * NCH + c) * 4096;   // [p][s]
    rg = Ccb; obase = h * 64; ostride = DI;
  }
  for (int gi = tid; gi < 4096; gi += 256)
    S0l[(gi & 63) * 68 + (gi >> 6)] = s0g[gi];
  {
    int t = tid >> 2, q = tid & 3;
    const float4* src = (const float4*)&rg[(size_t)(t0 + t) * ostride + obase + q * 16];
    float4* dst = (float4*)&Rl[t * 68 + q * 16];
    dst[0] = src[0]; dst[1] = src[1]; dst[2] = src[2]; dst[3] = src[3];
  }
  __syncthreads();
  int t = tid >> 2, q = (tid & 3) * 16;
  float acc[16];
#pragma unroll
  for (int j = 0; j < 16; j++) acc[j] = 0.f;
  for (int k = 0; k < 64; ++k) {
    float rv = Rl[t * 68 + k];
    const float4* sp = (const float4*)&S0l[k * 68 + q];
#pragma unroll
    for (int j4 = 0; j4 < 4; ++j4) {
      float4 s4 = sp[j4];
      acc[j4 * 4 + 0] = fmaf(rv, s4.x, acc[j4 * 4 + 0]);
      acc[j4 * 4 + 1] = fmaf(rv, s4.y, acc[j4 * 4 + 1]);
      acc[j4 * 4 + 2] = fmaf(rv, s4.z, acc[j4 * 4 + 2]);
      acc[j4 * 4 + 3] = fmaf(rv, s4.w, acc[j4 * 4 + 3]);
    }
  }
  if (!rwkv) {
    float4* op = (float4*)&yb[(size_t)(t0 + t) * DI + obase + q];
#pragma unroll
    for (int j4 = 0; j4 < 4; ++j4) {
      float4 cur = op[j4];
      cur.x += acc[j4 * 4 + 0]; cur.y += acc[j4 * 4 + 1];
      cur.z += acc[j4 * 4 + 2]; cur.w += acc[j4 * 4 + 3];
      op[j4] = cur;
    }
  } else {
    // o = so + corr; groupnorm over 64 (4 lanes x 16) then *silu(g) -> bf16
    float ov[16];
    const float4* sp = (const float4*)&so[(size_t)(t0 + t) * DD + obase + q];
#pragma unroll
    for (int j4 = 0; j4 < 4; ++j4) {
      float4 s4 = sp[j4];
      ov[j4 * 4 + 0] = s4.x + acc[j4 * 4 + 0];
      ov[j4 * 4 + 1] = s4.y + acc[j4 * 4 + 1];
      ov[j4 * 4 + 2] = s4.z + acc[j4 * 4 + 2];
      ov[j4 * 4 + 3] = s4.w + acc[j4 * 4 + 3];
    }
    float m_ = 0.f;
#pragma unroll
    for (int j = 0; j < 16; j++) m_ += ov[j];
    m_ += __shfl_xor(m_, 1); m_ += __shfl_xor(m_, 2);
    float mu = m_ * (1.f / 64.f);
    float vv = 0.f;
#pragma unroll
    for (int j = 0; j < 16; j++) { float d = ov[j] - mu; vv = fmaf(d, d, vv); }
    vv += __shfl_xor(vv, 1); vv += __shfl_xor(vv, 2);
    float rstd = rsqrtf(vv * (1.f / 64.f) + 1e-5f);
#pragma unroll
    for (int j = 0; j < 16; j++) {
      int d = obase + q + j;
      float gv = P[(size_t)(t0 + t) * PW + 1152 + d];
      float o = fmaf((ov[j] - mu) * rstd, gnw[d], gnb[d]) * siluf(gv);
      gob[(size_t)(t0 + t) * DD + d] = f2b(o);
    }
  }
}

// ---------------- Mamba conv1d (+bias, silu) ----------------
__global__ void conv_kernel(const float* __restrict__ zx, const float* __restrict__ cw,
                            const float* __restrict__ cb, float* __restrict__ out)
{
  int idx = blockIdx.x * 256 + threadIdx.x;
  if (idx >= TT * CONVC) return;
  int t = idx / CONVC, c = idx % CONVC;
  float acc = cb[c];
#pragma unroll
  for (int j = 0; j < 4; ++j) {
    int tt = t + j - 3;
    if (tt >= 0) acc = fmaf(zx[(size_t)tt * XDIM + DI + c], cw[c * 4 + j], acc);
  }
  out[idx] = siluf(acc);
}

// ---------------- Mamba out: rms(y * silu(z), mn_w) -> bf16 ----------------
__global__ __launch_bounds__(256) void mamba_norm_kernel(const float* __restrict__ yb,
    const float* __restrict__ zx, const float* __restrict__ mnw, unsigned short* __restrict__ out)
{
  int t = blockIdx.x;
  __shared__ float vbuf[DI];
  __shared__ float red[256];
  float ss = 0.f;
  for (int c = threadIdx.x; c < DI; c += 256) {
    float z = zx[(size_t)t * XDIM + c];
    float v = yb[(size_t)t * DI + c] * siluf(z);
    vbuf[c] = v;
    ss = fmaf(v, v, ss);
  }
  red[threadIdx.x] = ss; __syncthreads();
  for (int s = 128; s > 0; s >>= 1) {
    if (threadIdx.x < s) red[threadIdx.x] += red[threadIdx.x + s];
    __syncthreads();
  }
  float scale = rsqrtf(red[0] / DI + 1e-6f);
  for (int c = threadIdx.x; c < DI; c += 256)
    out[(size_t)t * DI + c] = f2b(vbuf[c] * scale * mnw[c]);
}

// ---------------- gate combine ----------------
__global__ __launch_bounds__(256) void gate_kernel(const float* __restrict__ orb,
    const float* __restrict__ omb, const float* __restrict__ gw,
    const float* __restrict__ gb, float* __restrict__ h)
{
  int t = blockIdx.x;
  float ss = 0.f;
  for (int c = threadIdx.x; c < DD; c += 256)
    ss += orb[(size_t)t * DD + c] * gw[c] + omb[(size_t)t * DD + c] * gw[DD + c];
  __shared__ float red[256];
  red[threadIdx.x] = ss; __syncthreads();
  for (int s = 128; s > 0; s >>= 1) {
    if (threadIdx.x < s) red[threadIdx.x] += red[threadIdx.x + s];
    __syncthreads();
  }
  float gate = sigmoidf_(red[0] + gb[0]);
  for (int c = threadIdx.x; c < DD; c += 256) {
    size_t ix = (size_t)t * DD + c;
    h[ix] += gate * orb[ix] + (1.f - gate) * omb[ix];
  }
}

// ---------------- launcher ----------------
extern "C" void kernel_launch(void* const* d_in, const int* in_sizes, int n_in,
                              void* d_out, int out_size, void* d_ws, size_t ws_size,
                              hipStream_t stream)
{
  const int*   x        = (const int*)  d_in[0];
  const float* embed    = (const float*)d_in[1];
  const float* ln_w     = (const float*)d_in[2];
  const float* Wr       = (const float*)d_in[3];
  const float* Wk       = (const float*)d_in[4];
  const float* Wv       = (const float*)d_in[5];
  const float* Wg       = (const float*)d_in[6];
  const float* Ww       = (const float*)d_in[7];
  const float* w_bias   = (const float*)d_in[8];
  const float* u        = (const float*)d_in[9];
  const float* gn_w     = (const float*)d_in[10];
  const float* gn_b     = (const float*)d_in[11];
  const float* Wo       = (const float*)d_in[12];
  const float* W_in     = (const float*)d_in[13];
  const float* conv_w   = (const float*)d_in[14];
  const float* conv_b   = (const float*)d_in[15];
  const float* dt_bias  = (const float*)d_in[16];
  const float* A_log    = (const float*)d_in[17];
  const float* Dp       = (const float*)d_in[18];
  const float* mn_w     = (const float*)d_in[19];
  const float* W_out    = (const float*)d_in[20];
  const float* gw       = (const float*)d_in[21];
  const float* gb       = (const float*)d_in[22];
  const float* ffn_ln_w = (const float*)d_in[23];
  const float* ffn_w1   = (const float*)d_in[24];
  const float* ffn_w2   = (const float*)d_in[25];
  const float* ln_out_w = (const float*)d_in[26];

  char* base = (char*)d_ws;
  size_t off = 0;
  auto alloc = [&](size_t bytes) { off = (off + 255) & ~(size_t)255; void* p = base + off; off += bytes; return p; };

  float* h    = (float*)alloc((size_t)TT * DD * 4);
  float* P    = (float*)alloc((size_t)TT * PW * 4);
  float* zx   = (float*)alloc((size_t)TT * XDIM * 4);
  float* xb   = (float*)alloc((size_t)TT * CONVC * 4);
  float* yb   = (float*)alloc((size_t)TT * DI * 4);
  float* so   = (float*)alloc((size_t)TT * DD * 4);
  float* orb  = (float*)alloc((size_t)TT * DD * 4);
  float* omb  = (float*)alloc((size_t)TT * DD * 4);
  float* rPb  = (float*)alloc((size_t)TT * DD * 4);
  float* Ccb  = (float*)alloc((size_t)TT * DI * 4);
  float* MstR = (float*)alloc((size_t)NH * NCH * 4096 * 4);
  float* DcR  = (float*)alloc((size_t)NH * NCH * 64 * 4);
  float* S0R  = (float*)alloc((size_t)NH * NCH * 4096 * 4);
  float* MstM = (float*)alloc((size_t)MH * NCH * 4096 * 4);
  float* DcM  = (float*)alloc((size_t)MH * NCH * 4);
  float* S0M  = (float*)alloc((size_t)MH * NCH * 4096 * 4);
  unsigned short* xnb = (unsigned short*)alloc((size_t)TT * DD * 2);
  unsigned short* gob = (unsigned short*)alloc((size_t)TT * DD * 2);
  unsigned short* ynb = (unsigned short*)alloc((size_t)TT * DI * 2);
  unsigned short* fhb = (unsigned short*)alloc((size_t)TT * 1536 * 2);
  unsigned short* WcatT = (unsigned short*)alloc((size_t)NL * PW * 384 * 2);
  unsigned short* WinT  = (unsigned short*)alloc((size_t)NL * 1792 * 384 * 2);
  unsigned short* WoT   = (unsigned short*)alloc((size_t)NL * 384 * 384 * 2);
  unsigned short* WoutT = (unsigned short*)alloc((size_t)NL * 384 * 768 * 2);
  unsigned short* F1T   = (unsigned short*)alloc((size_t)NL * 1536 * 384 * 2);
  unsigned short* F2T   = (unsigned short*)alloc((size_t)NL * 384 * 1536 * 2);
  unsigned short* embB  = (unsigned short*)alloc((size_t)NV * DD * 2);
  (void)ws_size; (void)in_sizes; (void)n_in; (void)out_size;

  dim3 blk(256);
  int gTD = (TT * DD + 255) / 256;

  // ---- one-time (per launch) weight conversion ----
  const float* Wrkvgw[5] = {Wr, Wk, Wv, Wg, Ww};
  for (int j = 0; j < 5; ++j)
    transconv_kernel<<<dim3(12, 12, 8), blk, 0, stream>>>(
        Wrkvgw[j], WcatT + (size_t)j * 384 * 384, 384, 384, 384,
        (size_t)384 * 384, (size_t)PW * 384);
  transconv_kernel<<<dim3(56, 12, 8), blk, 0, stream>>>(
      W_in, WinT, 384, XDIM, 1792, (size_t)384 * XDIM, (size_t)1792 * 384);
  transconv_kernel<<<dim3(12, 12, 8), blk, 0, stream>>>(
      Wo, WoT, 384, 384, 384, (size_t)384 * 384, (size_t)384 * 384);
  transconv_kernel<<<dim3(12, 24, 8), blk, 0, stream>>>(
      W_out, WoutT, 768, 384, 384, (size_t)768 * 384, (size_t)384 * 768);
  transconv_kernel<<<dim3(48, 12, 8), blk, 0, stream>>>(
      ffn_w1, F1T, 384, 1536, 1536, (size_t)384 * 1536, (size_t)1536 * 384);
  transconv_kernel<<<dim3(12, 48, 8), blk, 0, stream>>>(
      ffn_w2, F2T, 1536, 384, 384, (size_t)1536 * 384, (size_t)384 * 1536);
  conv_b16_kernel<<<(NV * DD + 255) / 256, blk, 0, stream>>>(embed, embB, NV * DD);

  embed_kernel<<<gTD, blk, 0, stream>>>(x, embed, h);

  for (int i = 0; i < NL; ++i) {
    rms_kernel<<<TT, blk, 0, stream>>>(h, ln_w + (size_t)i * DD, xnb, DD, 1e-6f);

    gemm128<0><<<dim3(15, 8), blk, 0, stream>>>(
        xnb, WcatT + (size_t)i * PW * 384, P, nullptr, PW, 384, PW);
    gemm128<0><<<dim3(14, 8), blk, 0, stream>>>(
        xnb, WinT + (size_t)i * 1792 * 384, zx, nullptr, XDIM, 384, XDIM);
    conv_kernel<<<(TT * CONVC + 255) / 256, blk, 0, stream>>>(
        zx, conv_w + (size_t)i * CONVC * 4, conv_b + (size_t)i * CONVC, xb);

    scanA_kernel<<<288, blk, 0, stream>>>(P, u + (size_t)i * NH * 64, w_bias + (size_t)i * DD,
                                          so, rPb, MstR, DcR,
                                          xb, zx, dt_bias + (size_t)i * MH,
                                          A_log + (size_t)i * MH, Dp + (size_t)i * MH,
                                          yb, Ccb, MstM, DcM);
    combine_kernel<<<288, blk, 0, stream>>>(MstR, DcR, S0R, MstM, DcM, S0M);
    corr_kernel<<<288, blk, 0, stream>>>(S0R, rPb, so, S0M, Ccb, yb,
                                         P, gn_w + (size_t)i * DD, gn_b + (size_t)i * DD, gob);

    gemm_bf16<0><<<dim3(6, 16), blk, 0, stream>>>(
        gob, WoT + (size_t)i * 384 * 384, orb, DD, 384, DD);

    mamba_norm_kernel<<<TT, blk, 0, stream>>>(yb, zx, mn_w + (size_t)i * DI, ynb);
    gemm_bf16<0><<<dim3(6, 16), blk, 0, stream>>>(
        ynb, WoutT + (size_t)i * 384 * 768, omb, DD, 768, DD);

    gate_kernel<<<TT, blk, 0, stream>>>(orb, omb, gw + (size_t)i * 2 * DD, gb + i, h);

    rms_kernel<<<TT, blk, 0, stream>>>(h, ffn_ln_w + (size_t)i * DD, xnb, DD, 1e-6f);
    gemm128<1><<<dim3(12, 8), blk, 0, stream>>>(
        xnb, F1T + (size_t)i * 1536 * 384, nullptr, fhb, 1536, 384, 1536);
    gemm_bf16<2><<<dim3(6, 16), blk, 0, stream>>>(
        fhb, F2T + (size_t)i * 384 * 1536, h, DD, 1536, DD);
  }

  rms_kernel<<<TT, blk, 0, stream>>>(h, ln_out_w, xnb, DD, 1e-6f);
  gemm128<0><<<dim3(250, 8), blk, 0, stream>>>(
      xnb, embB, (float*)d_out, nullptr, NV, 384, NV);
}

// Round 5
// 1183.634 us; speedup vs baseline: 1.3234x; 1.3234x over previous
//
#include <hip/hip_runtime.h>
#include <math.h>

#define TT 1024
#define DD 384
#define NH 6
#define DI 768
#define MH 12
#define DS 64
#define NL 8
#define XDIM 1676   // 2*DI + 2*DS + MH
#define CONVC 896   // DI + 2*DS
#define NV 32000
#define PZS 3712    // fused output width: [r|k|v|g|w](1920) + [z|xBC|dt](1792 padded)
#define G_OFF 1152
#define W_OFF 1536
#define Z_OFF 1920
#define XBC_OFF 2688   // Z_OFF + DI
#define DT_OFF 3584    // Z_OFF + 1664
#define CHK 32      // scan chunk length
#define NCH 32      // number of chunks

typedef __attribute__((ext_vector_type(8))) short short8;
typedef __attribute__((ext_vector_type(4))) float f32x4;

// ---------------- helpers ----------------
__device__ __forceinline__ float siluf(float x) { return x / (1.f + expf(-x)); }
__device__ __forceinline__ float sigmoidf_(float x) { return 1.f / (1.f + expf(-x)); }
__device__ __forceinline__ float geluf(float x) {
  return 0.5f * x * (1.f + erff(x * 0.70710678118654752440f));
}
__device__ __forceinline__ unsigned short f2b(float x) {
  union { float f; unsigned int u; } v; v.f = x;
  unsigned int r = v.u + 0x7fffu + ((v.u >> 16) & 1u);
  return (unsigned short)(r >> 16);
}

#define GLDS(gp, lp) __builtin_amdgcn_global_load_lds( \
    (const __attribute__((address_space(1))) void*)(gp), \
    (__attribute__((address_space(3))) void*)(lp), 16, 0, 0)

// ---------------- 64-tile bf16 MFMA GEMM. EPI: 0=store f32, 1=gelu->bf16, 2=add-residual ----------------
template<int EPI>
__global__ __launch_bounds__(256) void gemm_bf16(
    const unsigned short* __restrict__ A, const unsigned short* __restrict__ Bt,
    float* __restrict__ C, unsigned short* __restrict__ Cb, int N, int K, int ldC)
{
  __shared__ unsigned short As[2048];   // [64][32]
  __shared__ unsigned short Bs[2048];
  int tid = threadIdx.x;
  int wid = tid >> 6, lane = tid & 63;
  int m0 = blockIdx.y * 64, n0 = blockIdx.x * 64;
  int wr = wid >> 1, wc = wid & 1;
  int sr = tid >> 2;
  int scs = ((tid & 3) ^ ((sr >> 1) & 3)) * 8;
  const unsigned short* ga = A  + (size_t)(m0 + sr) * K + scs;
  const unsigned short* gb = Bt + (size_t)(n0 + sr) * K + scs;
  unsigned short* la = As + wid * 512;
  unsigned short* lb = Bs + wid * 512;
  int fr = lane & 15, fc = lane >> 4;
  f32x4 zz = {0.f, 0.f, 0.f, 0.f};
  f32x4 acc[2][2];
  acc[0][0] = zz; acc[0][1] = zz; acc[1][0] = zz; acc[1][1] = zz;

  for (int k0 = 0; k0 < K; k0 += 32) {
    GLDS(ga + k0, la);
    GLDS(gb + k0, lb);
    __syncthreads();
    short8 af[2], bf[2];
#pragma unroll
    for (int mg = 0; mg < 2; ++mg) {
      int ar = wr * 32 + mg * 16 + fr;
      af[mg] = *reinterpret_cast<const short8*>(&As[ar * 32 + ((fc ^ ((ar >> 1) & 3)) * 8)]);
    }
#pragma unroll
    for (int ng = 0; ng < 2; ++ng) {
      int br = wc * 32 + ng * 16 + fr;
      bf[ng] = *reinterpret_cast<const short8*>(&Bs[br * 32 + ((fc ^ ((br >> 1) & 3)) * 8)]);
    }
#pragma unroll
    for (int mg = 0; mg < 2; ++mg)
#pragma unroll
      for (int ng = 0; ng < 2; ++ng)
        acc[mg][ng] = __builtin_amdgcn_mfma_f32_16x16x32_bf16(af[mg], bf[ng], acc[mg][ng], 0, 0, 0);
    __syncthreads();
  }
#pragma unroll
  for (int mg = 0; mg < 2; ++mg)
#pragma unroll
    for (int ng = 0; ng < 2; ++ng) {
      int col = n0 + wc * 32 + ng * 16 + fr;
      if (col < N) {
#pragma unroll
        for (int j = 0; j < 4; ++j) {
          int row = m0 + wr * 32 + mg * 16 + fc * 4 + j;
          if (EPI == 1)      Cb[(size_t)row * ldC + col] = f2b(geluf(acc[mg][ng][j]));
          else if (EPI == 2) C[(size_t)row * ldC + col] += acc[mg][ng][j];
          else               C[(size_t)row * ldC + col]  = acc[mg][ng][j];
        }
      }
    }
}

// ---------------- 128-tile bf16 MFMA GEMM (logits) ----------------
__global__ __launch_bounds__(256) void gemm128(
    const unsigned short* __restrict__ A, const unsigned short* __restrict__ Bt,
    float* __restrict__ C, int N, int K, int ldC)
{
  __shared__ unsigned short As[4096];   // [128][32] (chunk-linear)
  __shared__ unsigned short Bs[4096];
  int tid = threadIdx.x;
  int wid = tid >> 6, lane = tid & 63;
  int m0 = blockIdx.y * 128, n0 = blockIdx.x * 128;
  int wr = wid >> 1, wc = wid & 1;
  int r0 = tid >> 2;
  int scs = ((tid & 3) ^ ((r0 >> 1) & 3)) * 8;
  const unsigned short* ga0 = A  + (size_t)(m0 + r0) * K + scs;
  const unsigned short* gb0 = Bt + (size_t)(n0 + r0) * K + scs;
  const unsigned short* ga1 = ga0 + (size_t)64 * K;
  const unsigned short* gb1 = gb0 + (size_t)64 * K;
  unsigned short* la0 = As + wid * 512;
  unsigned short* lb0 = Bs + wid * 512;
  unsigned short* la1 = As + 2048 + wid * 512;
  unsigned short* lb1 = Bs + 2048 + wid * 512;
  int fr = lane & 15, fc = lane >> 4;
  f32x4 zz = {0.f, 0.f, 0.f, 0.f};
  f32x4 acc[4][4];
#pragma unroll
  for (int i = 0; i < 4; i++)
#pragma unroll
    for (int j = 0; j < 4; j++) acc[i][j] = zz;

  for (int k0 = 0; k0 < K; k0 += 32) {
    GLDS(ga0 + k0, la0);
    GLDS(gb0 + k0, lb0);
    GLDS(ga1 + k0, la1);
    GLDS(gb1 + k0, lb1);
    __syncthreads();
    short8 af[4], bf[4];
#pragma unroll
    for (int mg = 0; mg < 4; ++mg) {
      int ar = wr * 64 + mg * 16 + fr;
      af[mg] = *reinterpret_cast<const short8*>(&As[ar * 32 + ((fc ^ ((ar >> 1) & 3)) * 8)]);
    }
#pragma unroll
    for (int ng = 0; ng < 4; ++ng) {
      int br = wc * 64 + ng * 16 + fr;
      bf[ng] = *reinterpret_cast<const short8*>(&Bs[br * 32 + ((fc ^ ((br >> 1) & 3)) * 8)]);
    }
#pragma unroll
    for (int mg = 0; mg < 4; ++mg)
#pragma unroll
      for (int ng = 0; ng < 4; ++ng)
        acc[mg][ng] = __builtin_amdgcn_mfma_f32_16x16x32_bf16(af[mg], bf[ng], acc[mg][ng], 0, 0, 0);
    __syncthreads();
  }
#pragma unroll
  for (int mg = 0; mg < 4; ++mg)
#pragma unroll
    for (int ng = 0; ng < 4; ++ng) {
      int col = n0 + wc * 64 + ng * 16 + fr;
      if (col < N) {
#pragma unroll
        for (int j = 0; j < 4; ++j) {
          int row = m0 + wr * 64 + mg * 16 + fc * 4 + j;
          C[(size_t)row * ldC + col] = acc[mg][ng][j];
        }
      }
    }
}

// ---------------- weight transpose + fp32->bf16 ----------------
__global__ __launch_bounds__(256) void transconv_kernel(
    const float* __restrict__ src, unsigned short* __restrict__ dst,
    int K, int N, int Npad, size_t srcStride, size_t dstStride)
{
  __shared__ float tile[32][33];
  src += (size_t)blockIdx.z * srcStride;
  dst += (size_t)blockIdx.z * dstStride;
  int k0 = blockIdx.y * 32, n0 = blockIdx.x * 32;
  int tx = threadIdx.x & 31, ty = threadIdx.x >> 5;
  for (int i = ty; i < 32; i += 8) {
    int k = k0 + i, n = n0 + tx;
    tile[i][tx] = (k < K && n < N) ? src[(size_t)k * N + n] : 0.f;
  }
  __syncthreads();
  for (int i = ty; i < 32; i += 8) {
    int n = n0 + i, k = k0 + tx;
    if (n < Npad && k < K) dst[(size_t)n * K + k] = f2b(tile[tx][i]);
  }
}

__global__ void conv_b16_kernel(const float* __restrict__ src, unsigned short* __restrict__ dst, int n)
{
  int idx = blockIdx.x * 256 + threadIdx.x;
  if (idx < n) dst[idx] = f2b(src[idx]);
}

// ---------------- embedding gather ----------------
__global__ void embed_kernel(const int* __restrict__ x, const float* __restrict__ embed,
                             float* __restrict__ h)
{
  int idx = blockIdx.x * 256 + threadIdx.x;
  if (idx < TT * DD) {
    int t = idx / DD, d = idx % DD;
    h[idx] = embed[(size_t)x[t] * DD + d];
  }
}

// ---------------- RMSNorm -> bf16 out ----------------
__global__ __launch_bounds__(256) void rms_kernel(const float* __restrict__ in,
                                                  const float* __restrict__ w,
                                                  unsigned short* __restrict__ out,
                                                  int ncol, float eps)
{
  int t = blockIdx.x;
  const float* row = in + (size_t)t * ncol;
  float ss = 0.f;
  for (int c = threadIdx.x; c < ncol; c += 256) { float v = row[c]; ss = fmaf(v, v, ss); }
  __shared__ float red[256];
  red[threadIdx.x] = ss; __syncthreads();
  for (int s = 128; s > 0; s >>= 1) {
    if (threadIdx.x < s) red[threadIdx.x] += red[threadIdx.x + s];
    __syncthreads();
  }
  float scale = rsqrtf(red[0] / ncol + eps);
  for (int c = threadIdx.x; c < ncol; c += 256) out[(size_t)t * ncol + c] = f2b(w[c] * row[c] * scale);
}

// ---------------- Phase A: per-chunk local scans (decay & dt fused) ----------------
// blocks 0..191: RWKV (h = b>>5, chunk c = b&31); 192..575: Mamba (hh, c)
__global__ __launch_bounds__(256) void scanA_kernel(
    const float* __restrict__ PZ, const float* __restrict__ u, const float* __restrict__ wbias,
    float* __restrict__ so, float* __restrict__ rPb,
    float* __restrict__ MstR, float* __restrict__ DcR,
    const float* __restrict__ xbc, const float* __restrict__ dtbias,
    const float* __restrict__ Alog, const float* __restrict__ Dpw,
    float* __restrict__ yb, float* __restrict__ Ccb,
    float* __restrict__ MstM, float* __restrict__ DcM)
{
  __shared__ float smem[2 * 256 + 64];
  int b = blockIdx.x, tid = threadIdx.x;
  if (b < 192) {
    int h = b >> 5, c = b & 31;
    float* sbuf = smem; float* us = smem + 512;
    if (tid < 64) us[tid] = u[h * 64 + tid];
    int wv = tid >> 6, l = tid & 63;
    int vv = wv * 16 + (l & 15);
    int kc = l >> 4;
    int arr = tid >> 6, idx = tid & 63;
    int off = (arr == 0) ? 0 : (arr == 1) ? 384 : (arr == 2) ? W_OFF : 768;  // r,k,w(raw),v
    float wb = (arr == 2) ? wbias[h * 64 + idx] : 0.f;
    size_t base = (size_t)h * 64 + idx + off;
    int t0 = c * CHK;
    float S[16], Pc[16];
#pragma unroll
    for (int i = 0; i < 16; i++) { S[i] = 0.f; Pc[i] = 1.f; }
    float reg = PZ[(size_t)t0 * PZS + base];
    bool st = (wv == 0) && ((l & 15) == 0);   // 4 threads, kc = 0..3
    for (int t = 0; t < CHK; ++t) {
      int tt = t0 + t;
      float* cb = sbuf + (t & 1) * 256;
      cb[arr * 64 + idx] = (arr == 2) ? expf(-expf(reg + wb)) : reg;
      if (t + 1 < CHK) reg = PZ[(size_t)(tt + 1) * PZS + base];
      __syncthreads();
      float vt = cb[192 + vv];
      float acc = 0.f;
      float rp[16];
#pragma unroll
      for (int i = 0; i < 16; ++i) {
        int kk = kc * 16 + i;
        float rv = cb[kk], kv = cb[64 + kk], dv = cb[128 + kk];
        rp[i] = rv * Pc[i];
        float kvv = kv * vt;
        acc = fmaf(rv, fmaf(us[kk], kvv, S[i]), acc);
        S[i] = fmaf(dv, S[i], kvv);
        Pc[i] *= dv;
      }
      acc += __shfl_xor(acc, 16);
      acc += __shfl_xor(acc, 32);
      if (l < 16) so[(size_t)tt * DD + h * 64 + vv] = acc;
      if (st) {
        float4* dst = (float4*)&rPb[(size_t)tt * DD + h * 64 + kc * 16];
        dst[0] = make_float4(rp[0], rp[1], rp[2], rp[3]);
        dst[1] = make_float4(rp[4], rp[5], rp[6], rp[7]);
        dst[2] = make_float4(rp[8], rp[9], rp[10], rp[11]);
        dst[3] = make_float4(rp[12], rp[13], rp[14], rp[15]);
      }
    }
    float* ms = MstR + (size_t)(h * NCH + c) * 4096;   // [v][k]
    float4* msv = (float4*)&ms[vv * 64 + kc * 16];
    msv[0] = make_float4(S[0], S[1], S[2], S[3]);
    msv[1] = make_float4(S[4], S[5], S[6], S[7]);
    msv[2] = make_float4(S[8], S[9], S[10], S[11]);
    msv[3] = make_float4(S[12], S[13], S[14], S[15]);
    if (st) {
      float4* dd_ = (float4*)&DcR[(h * NCH + c) * 64 + kc * 16];
      dd_[0] = make_float4(Pc[0], Pc[1], Pc[2], Pc[3]);
      dd_[1] = make_float4(Pc[4], Pc[5], Pc[6], Pc[7]);
      dd_[2] = make_float4(Pc[8], Pc[9], Pc[10], Pc[11]);
      dd_[3] = make_float4(Pc[12], Pc[13], Pc[14], Pc[15]);
    }
  } else {
    int bb = b - 192;
    int hh = bb >> 5, c = bb & 31;
    float* sbuf = smem;
    int wv = tid >> 6, l = tid & 63;
    int p = wv * 16 + (l & 15);
    int sc = l >> 4;
    int arr = tid >> 6, idx = tid & 63;
    float A = -expf(Alog[hh]);
    float Dph = Dpw[hh];
    float dtbh = dtbias[hh];
    int off = (arr == 0) ? (hh * 64 + idx) : (arr == 1) ? (DI + idx) : (DI + DS + idx);
    int t0 = c * CHK;
    float S[16]; float cdA = 1.f;
#pragma unroll
    for (int i = 0; i < 16; i++) S[i] = 0.f;
    float reg = (arr < 3) ? xbc[(size_t)t0 * CONVC + off]
                          : PZ[(size_t)t0 * PZS + DT_OFF + hh];
    bool st = (wv == 0) && ((l & 15) == 0);
    for (int t = 0; t < CHK; ++t) {
      int tt = t0 + t;
      float* cb = sbuf + (t & 1) * 256;
      if (arr < 3) cb[arr * 64 + idx] = reg;
      else if (idx == 0) {
        float v = reg + dtbh;
        cb[192] = (v > 20.f) ? v : log1pf(expf(v));
      }
      if (t + 1 < CHK) reg = (arr < 3) ? xbc[(size_t)(tt + 1) * CONVC + off]
                                       : PZ[(size_t)(tt + 1) * PZS + DT_OFF + hh];
      __syncthreads();
      float dt_ = cb[192];
      float dA = expf(dt_ * A);
      cdA *= dA;
      float xp = cb[p];
      float dtx = dt_ * xp;
      float acc = 0.f;
#pragma unroll
      for (int i = 0; i < 16; ++i) {
        int s = sc * 16 + i;
        S[i] = fmaf(dA, S[i], dtx * cb[64 + s]);
        acc = fmaf(S[i], cb[128 + s], acc);
      }
      acc += __shfl_xor(acc, 16);
      acc += __shfl_xor(acc, 32);
      if (l < 16) yb[(size_t)tt * DI + hh * 64 + p] = fmaf(Dph, xp, acc);
      if (st) {
        float4* dst = (float4*)&Ccb[(size_t)tt * DI + hh * 64 + sc * 16];
#pragma unroll
        for (int j4 = 0; j4 < 4; ++j4)
          dst[j4] = make_float4(cdA * cb[128 + sc * 16 + j4 * 4 + 0],
                                cdA * cb[128 + sc * 16 + j4 * 4 + 1],
                                cdA * cb[128 + sc * 16 + j4 * 4 + 2],
                                cdA * cb[128 + sc * 16 + j4 * 4 + 3]);
      }
    }
    float* ms = MstM + (size_t)(hh * NCH + c) * 4096;  // [p][s]
    float4* msv = (float4*)&ms[p * 64 + sc * 16];
    msv[0] = make_float4(S[0], S[1], S[2], S[3]);
    msv[1] = make_float4(S[4], S[5], S[6], S[7]);
    msv[2] = make_float4(S[8], S[9], S[10], S[11]);
    msv[3] = make_float4(S[12], S[13], S[14], S[15]);
    if (tid == 0) DcM[hh * NCH + c] = cdA;
  }
}

// ---------------- Phase B: chunk-state combine ----------------
__global__ __launch_bounds__(256) void combine_kernel(
    const float* __restrict__ MstR, const float* __restrict__ DcR, float* __restrict__ S0R,
    const float* __restrict__ MstM, const float* __restrict__ DcM, float* __restrict__ S0M)
{
  int b = blockIdx.x, tid = threadIdx.x;
  if (b < 96) {
    int h = b >> 4, sub = b & 15;
    int ei = sub * 256 + tid;         // element in [v][k]
    int k = ei & 63;
    float S = 0.f;
#pragma unroll
    for (int c = 0; c < NCH; ++c) {
      size_t base = (size_t)(h * NCH + c) * 4096;
      float m = MstR[base + ei];
      float dD = DcR[(h * NCH + c) * 64 + k];
      S0R[base + ei] = S;
      S = fmaf(dD, S, m);
    }
  } else {
    int bb = b - 96;
    int hh = bb >> 4, sub = bb & 15;
    int ei = sub * 256 + tid;
    float S = 0.f;
#pragma unroll
    for (int c = 0; c < NCH; ++c) {
      size_t base = (size_t)(hh * NCH + c) * 4096;
      float m = MstM[base + ei];
      float dD = DcM[hh * NCH + c];
      S0M[base + ei] = S;
      S = fmaf(dD, S, m);
    }
  }
}

// ---------------- Phase C: output correction (+ fused RWKV groupnorm*silu) ----------------
__global__ __launch_bounds__(256) void corr_kernel(
    const float* __restrict__ S0R, const float* __restrict__ rPb, const float* __restrict__ so,
    const float* __restrict__ S0M, const float* __restrict__ Ccb, float* __restrict__ yb,
    const float* __restrict__ PZ, const float* __restrict__ gnw, const float* __restrict__ gnb,
    unsigned short* __restrict__ gob)
{
  __shared__ float S0l[64 * 68];
  __shared__ float Rl[CHK * 68];
  int b = blockIdx.x, tid = threadIdx.x;
  const float* s0g; const float* rg; int ostride, obase, t0;
  bool rwkv = (b < 192);
  int h;
  if (rwkv) {
    h = b >> 5; int c = b & 31; t0 = c * CHK;
    s0g = S0R + (size_t)(h * NCH + c) * 4096;   // [v][k]
    rg = rPb; obase = h * 64; ostride = DD;
  } else {
    int bb = b - 192; h = bb >> 5; int c = bb & 31; t0 = c * CHK;
    s0g = S0M + (size_t)(h * NCH + c) * 4096;   // [p][s]
    rg = Ccb; obase = h * 64; ostride = DI;
  }
  for (int gi = tid; gi < 4096; gi += 256)
    S0l[(gi & 63) * 68 + (gi >> 6)] = s0g[gi];
  {
    int t = tid >> 3, q = (tid & 7) * 8;
    const float4* src = (const float4*)&rg[(size_t)(t0 + t) * ostride + obase + q];
    float4* dst = (float4*)&Rl[t * 68 + q];
    dst[0] = src[0]; dst[1] = src[1];
  }
  __syncthreads();
  int t = tid >> 3, q = (tid & 7) * 8;
  float acc[8];
#pragma unroll
  for (int j = 0; j < 8; j++) acc[j] = 0.f;
  for (int k = 0; k < 64; ++k) {
    float rv = Rl[t * 68 + k];
    const float4* sp = (const float4*)&S0l[k * 68 + q];
    float4 s0 = sp[0], s1 = sp[1];
    acc[0] = fmaf(rv, s0.x, acc[0]);
    acc[1] = fmaf(rv, s0.y, acc[1]);
    acc[2] = fmaf(rv, s0.z, acc[2]);
    acc[3] = fmaf(rv, s0.w, acc[3]);
    acc[4] = fmaf(rv, s1.x, acc[4]);
    acc[5] = fmaf(rv, s1.y, acc[5]);
    acc[6] = fmaf(rv, s1.z, acc[6]);
    acc[7] = fmaf(rv, s1.w, acc[7]);
  }
  if (!rwkv) {
    float4* op = (float4*)&yb[(size_t)(t0 + t) * DI + obase + q];
    float4 c0 = op[0], c1 = op[1];
    c0.x += acc[0]; c0.y += acc[1]; c0.z += acc[2]; c0.w += acc[3];
    c1.x += acc[4]; c1.y += acc[5]; c1.z += acc[6]; c1.w += acc[7];
    op[0] = c0; op[1] = c1;
  } else {
    float ov[8];
    const float4* sp = (const float4*)&so[(size_t)(t0 + t) * DD + obase + q];
    float4 s0 = sp[0], s1 = sp[1];
    ov[0] = s0.x + acc[0]; ov[1] = s0.y + acc[1]; ov[2] = s0.z + acc[2]; ov[3] = s0.w + acc[3];
    ov[4] = s1.x + acc[4]; ov[5] = s1.y + acc[5]; ov[6] = s1.z + acc[6]; ov[7] = s1.w + acc[7];
    float m_ = 0.f;
#pragma unroll
    for (int j = 0; j < 8; j++) m_ += ov[j];
    m_ += __shfl_xor(m_, 1); m_ += __shfl_xor(m_, 2); m_ += __shfl_xor(m_, 4);
    float mu = m_ * (1.f / 64.f);
    float vv = 0.f;
#pragma unroll
    for (int j = 0; j < 8; j++) { float d = ov[j] - mu; vv = fmaf(d, d, vv); }
    vv += __shfl_xor(vv, 1); vv += __shfl_xor(vv, 2); vv += __shfl_xor(vv, 4);
    float rstd = rsqrtf(vv * (1.f / 64.f) + 1e-5f);
#pragma unroll
    for (int j = 0; j < 8; j++) {
      int d = obase + q + j;
      float gv = PZ[(size_t)(t0 + t) * PZS + G_OFF + d];
      float o = fmaf((ov[j] - mu) * rstd, gnw[d], gnb[d]) * siluf(gv);
      gob[(size_t)(t0 + t) * DD + d] = f2b(o);
    }
  }
}

// ---------------- Mamba conv1d (+bias, silu) ----------------
__global__ void conv_kernel(const float* __restrict__ PZ, const float* __restrict__ cw,
                            const float* __restrict__ cb, float* __restrict__ out)
{
  int idx = blockIdx.x * 256 + threadIdx.x;
  if (idx >= TT * CONVC) return;
  int t = idx / CONVC, c = idx % CONVC;
  float acc = cb[c];
#pragma unroll
  for (int j = 0; j < 4; ++j) {
    int tt = t + j - 3;
    if (tt >= 0) acc = fmaf(PZ[(size_t)tt * PZS + XBC_OFF + c], cw[c * 4 + j], acc);
  }
  out[idx] = siluf(acc);
}

// ---------------- Mamba out: rms(y * silu(z), mn_w) -> bf16 ----------------
__global__ __launch_bounds__(256) void mamba_norm_kernel(const float* __restrict__ yb,
    const float* __restrict__ PZ, const float* __restrict__ mnw, unsigned short* __restrict__ out)
{
  int t = blockIdx.x;
  __shared__ float vbuf[DI];
  __shared__ float red[256];
  float ss = 0.f;
  for (int c = threadIdx.x; c < DI; c += 256) {
    float z = PZ[(size_t)t * PZS + Z_OFF + c];
    float v = yb[(size_t)t * DI + c] * siluf(z);
    vbuf[c] = v;
    ss = fmaf(v, v, ss);
  }
  red[threadIdx.x] = ss; __syncthreads();
  for (int s = 128; s > 0; s >>= 1) {
    if (threadIdx.x < s) red[threadIdx.x] += red[threadIdx.x + s];
    __syncthreads();
  }
  float scale = rsqrtf(red[0] / DI + 1e-6f);
  for (int c = threadIdx.x; c < DI; c += 256)
    out[(size_t)t * DI + c] = f2b(vbuf[c] * scale * mnw[c]);
}

// ---------------- gate combine + FFN RMSNorm fused ----------------
__global__ __launch_bounds__(256) void gate_rms_kernel(const float* __restrict__ orb,
    const float* __restrict__ omb, const float* __restrict__ gw,
    const float* __restrict__ gb, const float* __restrict__ flnw,
    float* __restrict__ h, unsigned short* __restrict__ xnb)
{
  int t = blockIdx.x;
  __shared__ float red[256];
  __shared__ float vbuf[DD];
  float ss = 0.f;
  for (int c = threadIdx.x; c < DD; c += 256)
    ss += orb[(size_t)t * DD + c] * gw[c] + omb[(size_t)t * DD + c] * gw[DD + c];
  red[threadIdx.x] = ss; __syncthreads();
  for (int s = 128; s > 0; s >>= 1) {
    if (threadIdx.x < s) red[threadIdx.x] += red[threadIdx.x + s];
    __syncthreads();
  }
  float gate = sigmoidf_(red[0] + gb[0]);
  __syncthreads();
  float ss2 = 0.f;
  for (int c = threadIdx.x; c < DD; c += 256) {
    size_t ix = (size_t)t * DD + c;
    float hn = h[ix] + gate * orb[ix] + (1.f - gate) * omb[ix];
    h[ix] = hn; vbuf[c] = hn;
    ss2 = fmaf(hn, hn, ss2);
  }
  red[threadIdx.x] = ss2; __syncthreads();
  for (int s = 128; s > 0; s >>= 1) {
    if (threadIdx.x < s) red[threadIdx.x] += red[threadIdx.x + s];
    __syncthreads();
  }
  float scale = rsqrtf(red[0] / DD + 1e-6f);
  for (int c = threadIdx.x; c < DD; c += 256)
    xnb[(size_t)t * DD + c] = f2b(flnw[c] * vbuf[c] * scale);
}

// ---------------- launcher ----------------
extern "C" void kernel_launch(void* const* d_in, const int* in_sizes, int n_in,
                              void* d_out, int out_size, void* d_ws, size_t ws_size,
                              hipStream_t stream)
{
  const int*   x        = (const int*)  d_in[0];
  const float* embed    = (const float*)d_in[1];
  const float* ln_w     = (const float*)d_in[2];
  const float* Wr       = (const float*)d_in[3];
  const float* Wk       = (const float*)d_in[4];
  const float* Wv       = (const float*)d_in[5];
  const float* Wg       = (const float*)d_in[6];
  const float* Ww       = (const float*)d_in[7];
  const float* w_bias   = (const float*)d_in[8];
  const float* u        = (const float*)d_in[9];
  const float* gn_w     = (const float*)d_in[10];
  const float* gn_b     = (const float*)d_in[11];
  const float* Wo       = (const float*)d_in[12];
  const float* W_in     = (const float*)d_in[13];
  const float* conv_w   = (const float*)d_in[14];
  const float* conv_b   = (const float*)d_in[15];
  const float* dt_bias  = (const float*)d_in[16];
  const float* A_log    = (const float*)d_in[17];
  const float* Dp       = (const float*)d_in[18];
  const float* mn_w     = (const float*)d_in[19];
  const float* W_out    = (const float*)d_in[20];
  const float* gw       = (const float*)d_in[21];
  const float* gb       = (const float*)d_in[22];
  const float* ffn_ln_w = (const float*)d_in[23];
  const float* ffn_w1   = (const float*)d_in[24];
  const float* ffn_w2   = (const float*)d_in[25];
  const float* ln_out_w = (const float*)d_in[26];

  char* base = (char*)d_ws;
  size_t off = 0;
  auto alloc = [&](size_t bytes) { off = (off + 255) & ~(size_t)255; void* p = base + off; off += bytes; return p; };

  float* h    = (float*)alloc((size_t)TT * DD * 4);
  float* PZ   = (float*)alloc((size_t)TT * PZS * 4);
  float* xb   = (float*)alloc((size_t)TT * CONVC * 4);
  float* yb   = (float*)alloc((size_t)TT * DI * 4);
  float* so   = (float*)alloc((size_t)TT * DD * 4);
  float* orb  = (float*)alloc((size_t)TT * DD * 4);
  float* omb  = (float*)alloc((size_t)TT * DD * 4);
  float* rPb  = (float*)alloc((size_t)TT * DD * 4);
  float* Ccb  = (float*)alloc((size_t)TT * DI * 4);
  float* MstR = (float*)alloc((size_t)NH * NCH * 4096 * 4);
  float* DcR  = (float*)alloc((size_t)NH * NCH * 64 * 4);
  float* S0R  = (float*)alloc((size_t)NH * NCH * 4096 * 4);
  float* MstM = (float*)alloc((size_t)MH * NCH * 4096 * 4);
  float* DcM  = (float*)alloc((size_t)MH * NCH * 4);
  float* S0M  = (float*)alloc((size_t)MH * NCH * 4096 * 4);
  unsigned short* xnb = (unsigned short*)alloc((size_t)TT * DD * 2);
  unsigned short* gob = (unsigned short*)alloc((size_t)TT * DD * 2);
  unsigned short* ynb = (unsigned short*)alloc((size_t)TT * DI * 2);
  unsigned short* fhb = (unsigned short*)alloc((size_t)TT * 1536 * 2);
  unsigned short* WallT = (unsigned short*)alloc((size_t)NL * PZS * 384 * 2);
  unsigned short* WoT   = (unsigned short*)alloc((size_t)NL * 384 * 384 * 2);
  unsigned short* WoutT = (unsigned short*)alloc((size_t)NL * 384 * 768 * 2);
  unsigned short* F1T   = (unsigned short*)alloc((size_t)NL * 1536 * 384 * 2);
  unsigned short* F2T   = (unsigned short*)alloc((size_t)NL * 384 * 1536 * 2);
  unsigned short* embB  = (unsigned short*)alloc((size_t)NV * DD * 2);
  (void)ws_size; (void)in_sizes; (void)n_in; (void)out_size;

  dim3 blk(256);
  int gTD = (TT * DD + 255) / 256;

  // ---- one-time (per launch) weight conversion: WallT rows [r|k|v|g|w|z..] ----
  const float* Wrkvgw[5] = {Wr, Wk, Wv, Wg, Ww};
  for (int j = 0; j < 5; ++j)
    transconv_kernel<<<dim3(12, 12, 8), blk, 0, stream>>>(
        Wrkvgw[j], WallT + (size_t)j * 384 * 384, 384, 384, 384,
        (size_t)384 * 384, (size_t)PZS * 384);
  transconv_kernel<<<dim3(56, 12, 8), blk, 0, stream>>>(
      W_in, WallT + (size_t)1920 * 384, 384, XDIM, 1792,
      (size_t)384 * XDIM, (size_t)PZS * 384);
  transconv_kernel<<<dim3(12, 12, 8), blk, 0, stream>>>(
      Wo, WoT, 384, 384, 384, (size_t)384 * 384, (size_t)384 * 384);
  transconv_kernel<<<dim3(12, 24, 8), blk, 0, stream>>>(
      W_out, WoutT, 768, 384, 384, (size_t)768 * 384, (size_t)384 * 768);
  transconv_kernel<<<dim3(48, 12, 8), blk, 0, stream>>>(
      ffn_w1, F1T, 384, 1536, 1536, (size_t)384 * 1536, (size_t)1536 * 384);
  transconv_kernel<<<dim3(12, 48, 8), blk, 0, stream>>>(
      ffn_w2, F2T, 1536, 384, 384, (size_t)1536 * 384, (size_t)384 * 1536);
  conv_b16_kernel<<<(NV * DD + 255) / 256, blk, 0, stream>>>(embed, embB, NV * DD);

  embed_kernel<<<gTD, blk, 0, stream>>>(x, embed, h);

  for (int i = 0; i < NL; ++i) {
    rms_kernel<<<TT, blk, 0, stream>>>(h, ln_w + (size_t)i * DD, xnb, DD, 1e-6f);

    gemm_bf16<0><<<dim3(58, 16), blk, 0, stream>>>(
        xnb, WallT + (size_t)i * PZS * 384, PZ, nullptr, PZS, 384, PZS);
    conv_kernel<<<(TT * CONVC + 255) / 256, blk, 0, stream>>>(
        PZ, conv_w + (size_t)i * CONVC * 4, conv_b + (size_t)i * CONVC, xb);

    scanA_kernel<<<576, blk, 0, stream>>>(PZ, u + (size_t)i * NH * 64, w_bias + (size_t)i * DD,
                                          so, rPb, MstR, DcR,
                                          xb, dt_bias + (size_t)i * MH,
                                          A_log + (size_t)i * MH, Dp + (size_t)i * MH,
                                          yb, Ccb, MstM, DcM);
    combine_kernel<<<288, blk, 0, stream>>>(MstR, DcR, S0R, MstM, DcM, S0M);
    corr_kernel<<<576, blk, 0, stream>>>(S0R, rPb, so, S0M, Ccb, yb,
                                         PZ, gn_w + (size_t)i * DD, gn_b + (size_t)i * DD, gob);

    gemm_bf16<0><<<dim3(6, 16), blk, 0, stream>>>(
        gob, WoT + (size_t)i * 384 * 384, orb, nullptr, DD, 384, DD);

    mamba_norm_kernel<<<TT, blk, 0, stream>>>(yb, PZ, mn_w + (size_t)i * DI, ynb);
    gemm_bf16<0><<<dim3(6, 16), blk, 0, stream>>>(
        ynb, WoutT + (size_t)i * 384 * 768, omb, nullptr, DD, 768, DD);

    gate_rms_kernel<<<TT, blk, 0, stream>>>(orb, omb, gw + (size_t)i * 2 * DD, gb + i,
                                            ffn_ln_w + (size_t)i * DD, h, xnb);

    gemm_bf16<1><<<dim3(24, 16), blk, 0, stream>>>(
        xnb, F1T + (size_t)i * 1536 * 384, nullptr, fhb, 1536, 384, 1536);
    gemm_bf16<2><<<dim3(6, 16), blk, 0, stream>>>(
        fhb, F2T + (size_t)i * 384 * 1536, h, nullptr, DD, 1536, DD);
  }

  rms_kernel<<<TT, blk, 0, stream>>>(h, ln_out_w, xnb, DD, 1e-6f);
  gemm128<<<dim3(250, 8), blk, 0, stream>>>(
      xnb, embB, (float*)d_out, NV, 384, NV);
}

// Round 6
// 980.597 us; speedup vs baseline: 1.5974x; 1.2071x over previous
//
#include <hip/hip_runtime.h>
#include <math.h>

#define TT 1024
#define DD 384
#define NH 6
#define DI 768
#define MH 12
#define DS 64
#define NL 8
#define XDIM 1676   // 2*DI + 2*DS + MH
#define CONVC 896   // DI + 2*DS
#define NV 32000
#define PZS 3712    // fused output width: [r|k|v|g|w](1920) + [z|xBC|dt](1792 padded)
#define G_OFF 1152
#define W_OFF 1536
#define Z_OFF 1920
#define XBC_OFF 2688   // Z_OFF + DI
#define DT_OFF 3584    // Z_OFF + 1664
#define CHK 32      // scan chunk length
#define NCH 32      // number of chunks

typedef __attribute__((ext_vector_type(8))) short short8;
typedef __attribute__((ext_vector_type(4))) float f32x4;

// ---------------- helpers ----------------
__device__ __forceinline__ float siluf(float x) { return x / (1.f + expf(-x)); }
__device__ __forceinline__ float sigmoidf_(float x) { return 1.f / (1.f + expf(-x)); }
__device__ __forceinline__ float geluf(float x) {
  return 0.5f * x * (1.f + erff(x * 0.70710678118654752440f));
}
__device__ __forceinline__ unsigned short f2b(float x) {
  union { float f; unsigned int u; } v; v.f = x;
  unsigned int r = v.u + 0x7fffu + ((v.u >> 16) & 1u);
  return (unsigned short)(r >> 16);
}

#define GLDS(gp, lp) __builtin_amdgcn_global_load_lds( \
    (const __attribute__((address_space(1))) void*)(gp), \
    (__attribute__((address_space(3))) void*)(lp), 16, 0, 0)

// ---------------- 64-tile bf16 MFMA GEMM. EPI: 0=store f32, 1=gelu->bf16, 3=atomic-add f32 ----------------
// Split-K via gridDim.z (K must be divisible by 32*gridDim.z).
template<int EPI>
__global__ __launch_bounds__(256) void gemm_bf16(
    const unsigned short* __restrict__ A, const unsigned short* __restrict__ Bt,
    float* __restrict__ C, unsigned short* __restrict__ Cb, int N, int K, int ldC)
{
  __shared__ unsigned short As[2048];   // [64][32]
  __shared__ unsigned short Bs[2048];
  int tid = threadIdx.x;
  int wid = tid >> 6, lane = tid & 63;
  int m0 = blockIdx.y * 64, n0 = blockIdx.x * 64;
  int wr = wid >> 1, wc = wid & 1;
  int sr = tid >> 2;
  int scs = ((tid & 3) ^ ((sr >> 1) & 3)) * 8;
  const unsigned short* ga = A  + (size_t)(m0 + sr) * K + scs;
  const unsigned short* gb = Bt + (size_t)(n0 + sr) * K + scs;
  unsigned short* la = As + wid * 512;
  unsigned short* lb = Bs + wid * 512;
  int fr = lane & 15, fc = lane >> 4;
  f32x4 zz = {0.f, 0.f, 0.f, 0.f};
  f32x4 acc[2][2];
  acc[0][0] = zz; acc[0][1] = zz; acc[1][0] = zz; acc[1][1] = zz;

  int kper = K / (int)gridDim.z;
  int ks = blockIdx.z * kper, ke = ks + kper;
  for (int k0 = ks; k0 < ke; k0 += 32) {
    GLDS(ga + k0, la);
    GLDS(gb + k0, lb);
    __syncthreads();
    short8 af[2], bf[2];
#pragma unroll
    for (int mg = 0; mg < 2; ++mg) {
      int ar = wr * 32 + mg * 16 + fr;
      af[mg] = *reinterpret_cast<const short8*>(&As[ar * 32 + ((fc ^ ((ar >> 1) & 3)) * 8)]);
    }
#pragma unroll
    for (int ng = 0; ng < 2; ++ng) {
      int br = wc * 32 + ng * 16 + fr;
      bf[ng] = *reinterpret_cast<const short8*>(&Bs[br * 32 + ((fc ^ ((br >> 1) & 3)) * 8)]);
    }
#pragma unroll
    for (int mg = 0; mg < 2; ++mg)
#pragma unroll
      for (int ng = 0; ng < 2; ++ng)
        acc[mg][ng] = __builtin_amdgcn_mfma_f32_16x16x32_bf16(af[mg], bf[ng], acc[mg][ng], 0, 0, 0);
    __syncthreads();
  }
#pragma unroll
  for (int mg = 0; mg < 2; ++mg)
#pragma unroll
    for (int ng = 0; ng < 2; ++ng) {
      int col = n0 + wc * 32 + ng * 16 + fr;
      if (col < N) {
#pragma unroll
        for (int j = 0; j < 4; ++j) {
          int row = m0 + wr * 32 + mg * 16 + fc * 4 + j;
          if (EPI == 1)      Cb[(size_t)row * ldC + col] = f2b(geluf(acc[mg][ng][j]));
          else if (EPI == 3) atomicAdd(&C[(size_t)row * ldC + col], acc[mg][ng][j]);
          else               C[(size_t)row * ldC + col]  = acc[mg][ng][j];
        }
      }
    }
}

// ---------------- dual 64-tile GEMM: blocks [0,nb0) run gemm0, rest gemm1 (both N%64==0, f32 store) ----------------
__global__ __launch_bounds__(256) void gemm_dual(
    const unsigned short* __restrict__ A0, const unsigned short* __restrict__ B0t,
    float* __restrict__ C0, int K0, int ld0, int nx0, int nb0,
    const unsigned short* __restrict__ A1, const unsigned short* __restrict__ B1t,
    float* __restrict__ C1, int K1, int ld1, int nx1)
{
  __shared__ unsigned short As[2048];
  __shared__ unsigned short Bs[2048];
  int b = blockIdx.x;
  const unsigned short *A, *Bt; float* C; int K, ldC, bx, by;
  if (b < nb0) { A = A0; Bt = B0t; C = C0; K = K0; ldC = ld0; bx = b % nx0; by = b / nx0; }
  else { b -= nb0; A = A1; Bt = B1t; C = C1; K = K1; ldC = ld1; bx = b % nx1; by = b / nx1; }
  int tid = threadIdx.x;
  int wid = tid >> 6, lane = tid & 63;
  int m0 = by * 64, n0 = bx * 64;
  int wr = wid >> 1, wc = wid & 1;
  int sr = tid >> 2;
  int scs = ((tid & 3) ^ ((sr >> 1) & 3)) * 8;
  const unsigned short* ga = A  + (size_t)(m0 + sr) * K + scs;
  const unsigned short* gb = Bt + (size_t)(n0 + sr) * K + scs;
  unsigned short* la = As + wid * 512;
  unsigned short* lb = Bs + wid * 512;
  int fr = lane & 15, fc = lane >> 4;
  f32x4 zz = {0.f, 0.f, 0.f, 0.f};
  f32x4 acc[2][2];
  acc[0][0] = zz; acc[0][1] = zz; acc[1][0] = zz; acc[1][1] = zz;
  for (int k0 = 0; k0 < K; k0 += 32) {
    GLDS(ga + k0, la);
    GLDS(gb + k0, lb);
    __syncthreads();
    short8 af[2], bf[2];
#pragma unroll
    for (int mg = 0; mg < 2; ++mg) {
      int ar = wr * 32 + mg * 16 + fr;
      af[mg] = *reinterpret_cast<const short8*>(&As[ar * 32 + ((fc ^ ((ar >> 1) & 3)) * 8)]);
    }
#pragma unroll
    for (int ng = 0; ng < 2; ++ng) {
      int br = wc * 32 + ng * 16 + fr;
      bf[ng] = *reinterpret_cast<const short8*>(&Bs[br * 32 + ((fc ^ ((br >> 1) & 3)) * 8)]);
    }
#pragma unroll
    for (int mg = 0; mg < 2; ++mg)
#pragma unroll
      for (int ng = 0; ng < 2; ++ng)
        acc[mg][ng] = __builtin_amdgcn_mfma_f32_16x16x32_bf16(af[mg], bf[ng], acc[mg][ng], 0, 0, 0);
    __syncthreads();
  }
#pragma unroll
  for (int mg = 0; mg < 2; ++mg)
#pragma unroll
    for (int ng = 0; ng < 2; ++ng) {
      int col = n0 + wc * 32 + ng * 16 + fr;
#pragma unroll
      for (int j = 0; j < 4; ++j) {
        int row = m0 + wr * 32 + mg * 16 + fc * 4 + j;
        C[(size_t)row * ldC + col] = acc[mg][ng][j];
      }
    }
}

// ---------------- 128-tile bf16 MFMA GEMM (logits) ----------------
__global__ __launch_bounds__(256) void gemm128(
    const unsigned short* __restrict__ A, const unsigned short* __restrict__ Bt,
    float* __restrict__ C, int N, int K, int ldC)
{
  __shared__ unsigned short As[4096];   // [128][32] (chunk-linear)
  __shared__ unsigned short Bs[4096];
  int tid = threadIdx.x;
  int wid = tid >> 6, lane = tid & 63;
  int m0 = blockIdx.y * 128, n0 = blockIdx.x * 128;
  int wr = wid >> 1, wc = wid & 1;
  int r0 = tid >> 2;
  int scs = ((tid & 3) ^ ((r0 >> 1) & 3)) * 8;
  const unsigned short* ga0 = A  + (size_t)(m0 + r0) * K + scs;
  const unsigned short* gb0 = Bt + (size_t)(n0 + r0) * K + scs;
  const unsigned short* ga1 = ga0 + (size_t)64 * K;
  const unsigned short* gb1 = gb0 + (size_t)64 * K;
  unsigned short* la0 = As + wid * 512;
  unsigned short* lb0 = Bs + wid * 512;
  unsigned short* la1 = As + 2048 + wid * 512;
  unsigned short* lb1 = Bs + 2048 + wid * 512;
  int fr = lane & 15, fc = lane >> 4;
  f32x4 zz = {0.f, 0.f, 0.f, 0.f};
  f32x4 acc[4][4];
#pragma unroll
  for (int i = 0; i < 4; i++)
#pragma unroll
    for (int j = 0; j < 4; j++) acc[i][j] = zz;

  for (int k0 = 0; k0 < K; k0 += 32) {
    GLDS(ga0 + k0, la0);
    GLDS(gb0 + k0, lb0);
    GLDS(ga1 + k0, la1);
    GLDS(gb1 + k0, lb1);
    __syncthreads();
    short8 af[4], bf[4];
#pragma unroll
    for (int mg = 0; mg < 4; ++mg) {
      int ar = wr * 64 + mg * 16 + fr;
      af[mg] = *reinterpret_cast<const short8*>(&As[ar * 32 + ((fc ^ ((ar >> 1) & 3)) * 8)]);
    }
#pragma unroll
    for (int ng = 0; ng < 4; ++ng) {
      int br = wc * 64 + ng * 16 + fr;
      bf[ng] = *reinterpret_cast<const short8*>(&Bs[br * 32 + ((fc ^ ((br >> 1) & 3)) * 8)]);
    }
#pragma unroll
    for (int mg = 0; mg < 4; ++mg)
#pragma unroll
      for (int ng = 0; ng < 4; ++ng)
        acc[mg][ng] = __builtin_amdgcn_mfma_f32_16x16x32_bf16(af[mg], bf[ng], acc[mg][ng], 0, 0, 0);
    __syncthreads();
  }
#pragma unroll
  for (int mg = 0; mg < 4; ++mg)
#pragma unroll
    for (int ng = 0; ng < 4; ++ng) {
      int col = n0 + wc * 64 + ng * 16 + fr;
      if (col < N) {
#pragma unroll
        for (int j = 0; j < 4; ++j) {
          int row = m0 + wr * 64 + mg * 16 + fc * 4 + j;
          C[(size_t)row * ldC + col] = acc[mg][ng][j];
        }
      }
    }
}

// ---------------- weight transpose + fp32->bf16 ----------------
__global__ __launch_bounds__(256) void transconv_kernel(
    const float* __restrict__ src, unsigned short* __restrict__ dst,
    int K, int N, int Npad, size_t srcStride, size_t dstStride)
{
  __shared__ float tile[32][33];
  src += (size_t)blockIdx.z * srcStride;
  dst += (size_t)blockIdx.z * dstStride;
  int k0 = blockIdx.y * 32, n0 = blockIdx.x * 32;
  int tx = threadIdx.x & 31, ty = threadIdx.x >> 5;
  for (int i = ty; i < 32; i += 8) {
    int k = k0 + i, n = n0 + tx;
    tile[i][tx] = (k < K && n < N) ? src[(size_t)k * N + n] : 0.f;
  }
  __syncthreads();
  for (int i = ty; i < 32; i += 8) {
    int n = n0 + i, k = k0 + tx;
    if (n < Npad && k < K) dst[(size_t)n * K + k] = f2b(tile[tx][i]);
  }
}

__global__ void conv_b16_kernel(const float* __restrict__ src, unsigned short* __restrict__ dst, int n)
{
  int idx = blockIdx.x * 256 + threadIdx.x;
  if (idx < n) dst[idx] = f2b(src[idx]);
}

// ---------------- embedding gather ----------------
__global__ void embed_kernel(const int* __restrict__ x, const float* __restrict__ embed,
                             float* __restrict__ h)
{
  int idx = blockIdx.x * 256 + threadIdx.x;
  if (idx < TT * DD) {
    int t = idx / DD, d = idx % DD;
    h[idx] = embed[(size_t)x[t] * DD + d];
  }
}

// ---------------- RMSNorm (wave per row) -> bf16 ----------------
__global__ __launch_bounds__(256) void rms_kernel(const float* __restrict__ in,
                                                  const float* __restrict__ w,
                                                  unsigned short* __restrict__ out)
{
  int row = blockIdx.x * 4 + (threadIdx.x >> 6);
  int lane = threadIdx.x & 63;
  const float* r = in + (size_t)row * DD;
  float v[6]; float ss = 0.f;
#pragma unroll
  for (int j = 0; j < 6; ++j) { v[j] = r[lane + j * 64]; ss = fmaf(v[j], v[j], ss); }
#pragma unroll
  for (int s = 1; s < 64; s <<= 1) ss += __shfl_xor(ss, s);
  float scale = rsqrtf(ss * (1.f / DD) + 1e-6f);
#pragma unroll
  for (int j = 0; j < 6; ++j)
    out[(size_t)row * DD + lane + j * 64] = f2b(w[lane + j * 64] * v[j] * scale);
}

// ---------------- Phase A: per-chunk local scans (decay, dt, conv1d all fused) ----------------
// blocks 0..191: RWKV (h = b>>5, chunk c = b&31); 192..575: Mamba (hh, c)
__global__ __launch_bounds__(256) void scanA_kernel(
    const float* __restrict__ PZ, const float* __restrict__ u, const float* __restrict__ wbias,
    float* __restrict__ so, float* __restrict__ rPb,
    float* __restrict__ MstR, float* __restrict__ DcR,
    const float* __restrict__ cw, const float* __restrict__ cbia,
    const float* __restrict__ dtbias,
    const float* __restrict__ Alog, const float* __restrict__ Dpw,
    float* __restrict__ yb, float* __restrict__ Ccb,
    float* __restrict__ MstM, float* __restrict__ DcM)
{
  __shared__ float smem[2 * 256 + 64];
  int b = blockIdx.x, tid = threadIdx.x;
  if (b < 192) {
    int h = b >> 5, c = b & 31;
    float* sbuf = smem; float* us = smem + 512;
    if (tid < 64) us[tid] = u[h * 64 + tid];
    int wv = tid >> 6, l = tid & 63;
    int vv = wv * 16 + (l & 15);
    int kc = l >> 4;
    int arr = tid >> 6, idx = tid & 63;
    int off = (arr == 0) ? 0 : (arr == 1) ? 384 : (arr == 2) ? W_OFF : 768;  // r,k,w(raw),v
    float wb = (arr == 2) ? wbias[h * 64 + idx] : 0.f;
    size_t base = (size_t)h * 64 + idx + off;
    int t0 = c * CHK;
    float S[16], Pc[16];
#pragma unroll
    for (int i = 0; i < 16; i++) { S[i] = 0.f; Pc[i] = 1.f; }
    float reg = PZ[(size_t)t0 * PZS + base];
    bool st = (wv == 0) && ((l & 15) == 0);   // 4 threads, kc = 0..3
    for (int t = 0; t < CHK; ++t) {
      int tt = t0 + t;
      float* cb = sbuf + (t & 1) * 256;
      cb[arr * 64 + idx] = (arr == 2) ? expf(-expf(reg + wb)) : reg;
      if (t + 1 < CHK) reg = PZ[(size_t)(tt + 1) * PZS + base];
      __syncthreads();
      float vt = cb[192 + vv];
      float acc = 0.f;
      float rp[16];
#pragma unroll
      for (int i = 0; i < 16; ++i) {
        int kk = kc * 16 + i;
        float rv = cb[kk], kv = cb[64 + kk], dv = cb[128 + kk];
        rp[i] = rv * Pc[i];
        float kvv = kv * vt;
        acc = fmaf(rv, fmaf(us[kk], kvv, S[i]), acc);
        S[i] = fmaf(dv, S[i], kvv);
        Pc[i] *= dv;
      }
      acc += __shfl_xor(acc, 16);
      acc += __shfl_xor(acc, 32);
      if (l < 16) so[(size_t)tt * DD + h * 64 + vv] = acc;
      if (st) {
        float4* dst = (float4*)&rPb[(size_t)tt * DD + h * 64 + kc * 16];
        dst[0] = make_float4(rp[0], rp[1], rp[2], rp[3]);
        dst[1] = make_float4(rp[4], rp[5], rp[6], rp[7]);
        dst[2] = make_float4(rp[8], rp[9], rp[10], rp[11]);
        dst[3] = make_float4(rp[12], rp[13], rp[14], rp[15]);
      }
    }
    float* ms = MstR + (size_t)(h * NCH + c) * 4096;   // [v][k]
    float4* msv = (float4*)&ms[vv * 64 + kc * 16];
    msv[0] = make_float4(S[0], S[1], S[2], S[3]);
    msv[1] = make_float4(S[4], S[5], S[6], S[7]);
    msv[2] = make_float4(S[8], S[9], S[10], S[11]);
    msv[3] = make_float4(S[12], S[13], S[14], S[15]);
    if (st) {
      float4* dd_ = (float4*)&DcR[(h * NCH + c) * 64 + kc * 16];
      dd_[0] = make_float4(Pc[0], Pc[1], Pc[2], Pc[3]);
      dd_[1] = make_float4(Pc[4], Pc[5], Pc[6], Pc[7]);
      dd_[2] = make_float4(Pc[8], Pc[9], Pc[10], Pc[11]);
      dd_[3] = make_float4(Pc[12], Pc[13], Pc[14], Pc[15]);
    }
  } else {
    int bb = b - 192;
    int hh = bb >> 5, c = bb & 31;
    float* sbuf = smem;
    int wv = tid >> 6, l = tid & 63;
    int p = wv * 16 + (l & 15);
    int sc = l >> 4;
    int arr = tid >> 6, idx = tid & 63;
    float A = -expf(Alog[hh]);
    float Dph = Dpw[hh];
    float dtbh = dtbias[hh];
    int t0 = c * CHK;
    // conv state (arr<3): rolling 4-tap window on raw xBC channel
    float cw0 = 0.f, cw1 = 0.f, cw2 = 0.f, cw3 = 0.f, cbv = 0.f;
    float xw0 = 0.f, xw1 = 0.f, xw2 = 0.f, cur = 0.f;
    const float* xcol = nullptr;
    float reg = 0.f;
    if (arr < 3) {
      int ch = (arr == 0) ? (hh * 64 + idx) : (arr == 1) ? (DI + idx) : (DI + DS + idx);
      cw0 = cw[ch * 4 + 0]; cw1 = cw[ch * 4 + 1]; cw2 = cw[ch * 4 + 2]; cw3 = cw[ch * 4 + 3];
      cbv = cbia[ch];
      xcol = PZ + XBC_OFF + ch;
      xw0 = (t0 >= 3) ? xcol[(size_t)(t0 - 3) * PZS] : 0.f;
      xw1 = (t0 >= 2) ? xcol[(size_t)(t0 - 2) * PZS] : 0.f;
      xw2 = (t0 >= 1) ? xcol[(size_t)(t0 - 1) * PZS] : 0.f;
      cur = xcol[(size_t)t0 * PZS];
    } else {
      reg = PZ[(size_t)t0 * PZS + DT_OFF + hh];
    }
    float S[16]; float cdA = 1.f;
#pragma unroll
    for (int i = 0; i < 16; i++) S[i] = 0.f;
    bool st = (wv == 0) && ((l & 15) == 0);
    for (int t = 0; t < CHK; ++t) {
      int tt = t0 + t;
      float* cb = sbuf + (t & 1) * 256;
      if (arr < 3) {
        float cvv = fmaf(cw3, cur, fmaf(cw2, xw2, fmaf(cw1, xw1, fmaf(cw0, xw0, cbv))));
        cb[arr * 64 + idx] = siluf(cvv);
        float nx = (t + 1 < CHK) ? xcol[(size_t)(tt + 1) * PZS] : 0.f;
        xw0 = xw1; xw1 = xw2; xw2 = cur; cur = nx;
      } else {
        if (idx == 0) {
          float v = reg + dtbh;
          cb[192] = (v > 20.f) ? v : log1pf(expf(v));
        }
        if (t + 1 < CHK) reg = PZ[(size_t)(tt + 1) * PZS + DT_OFF + hh];
      }
      __syncthreads();
      float dt_ = cb[192];
      float dA = expf(dt_ * A);
      cdA *= dA;
      float xp = cb[p];
      float dtx = dt_ * xp;
      float acc = 0.f;
#pragma unroll
      for (int i = 0; i < 16; ++i) {
        int s = sc * 16 + i;
        S[i] = fmaf(dA, S[i], dtx * cb[64 + s]);
        acc = fmaf(S[i], cb[128 + s], acc);
      }
      acc += __shfl_xor(acc, 16);
      acc += __shfl_xor(acc, 32);
      if (l < 16) yb[(size_t)tt * DI + hh * 64 + p] = fmaf(Dph, xp, acc);
      if (st) {
        float4* dst = (float4*)&Ccb[(size_t)tt * DI + hh * 64 + sc * 16];
#pragma unroll
        for (int j4 = 0; j4 < 4; ++j4)
          dst[j4] = make_float4(cdA * cb[128 + sc * 16 + j4 * 4 + 0],
                                cdA * cb[128 + sc * 16 + j4 * 4 + 1],
                                cdA * cb[128 + sc * 16 + j4 * 4 + 2],
                                cdA * cb[128 + sc * 16 + j4 * 4 + 3]);
      }
    }
    float* ms = MstM + (size_t)(hh * NCH + c) * 4096;  // [p][s]
    float4* msv = (float4*)&ms[p * 64 + sc * 16];
    msv[0] = make_float4(S[0], S[1], S[2], S[3]);
    msv[1] = make_float4(S[4], S[5], S[6], S[7]);
    msv[2] = make_float4(S[8], S[9], S[10], S[11]);
    msv[3] = make_float4(S[12], S[13], S[14], S[15]);
    if (tid == 0) DcM[hh * NCH + c] = cdA;
  }
}

// ---------------- Phase B: chunk-state combine ----------------
__global__ __launch_bounds__(256) void combine_kernel(
    const float* __restrict__ MstR, const float* __restrict__ DcR, float* __restrict__ S0R,
    const float* __restrict__ MstM, const float* __restrict__ DcM, float* __restrict__ S0M)
{
  int b = blockIdx.x, tid = threadIdx.x;
  if (b < 96) {
    int h = b >> 4, sub = b & 15;
    int ei = sub * 256 + tid;         // element in [v][k]
    int k = ei & 63;
    float S = 0.f;
#pragma unroll
    for (int c = 0; c < NCH; ++c) {
      size_t base = (size_t)(h * NCH + c) * 4096;
      float m = MstR[base + ei];
      float dD = DcR[(h * NCH + c) * 64 + k];
      S0R[base + ei] = S;
      S = fmaf(dD, S, m);
    }
  } else {
    int bb = b - 96;
    int hh = bb >> 4, sub = bb & 15;
    int ei = sub * 256 + tid;
    float S = 0.f;
#pragma unroll
    for (int c = 0; c < NCH; ++c) {
      size_t base = (size_t)(hh * NCH + c) * 4096;
      float m = MstM[base + ei];
      float dD = DcM[hh * NCH + c];
      S0M[base + ei] = S;
      S = fmaf(dD, S, m);
    }
  }
}

// ---------------- Phase C: output correction (+ fused RWKV groupnorm*silu) ----------------
__global__ __launch_bounds__(256) void corr_kernel(
    const float* __restrict__ S0R, const float* __restrict__ rPb, const float* __restrict__ so,
    const float* __restrict__ S0M, const float* __restrict__ Ccb, float* __restrict__ yb,
    const float* __restrict__ PZ, const float* __restrict__ gnw, const float* __restrict__ gnb,
    unsigned short* __restrict__ gob)
{
  __shared__ float S0l[64 * 68];
  __shared__ float Rl[CHK * 68];
  int b = blockIdx.x, tid = threadIdx.x;
  const float* s0g; const float* rg; int ostride, obase, t0;
  bool rwkv = (b < 192);
  int h;
  if (rwkv) {
    h = b >> 5; int c = b & 31; t0 = c * CHK;
    s0g = S0R + (size_t)(h * NCH + c) * 4096;   // [v][k]
    rg = rPb; obase = h * 64; ostride = DD;
  } else {
    int bb = b - 192; h = bb >> 5; int c = bb & 31; t0 = c * CHK;
    s0g = S0M + (size_t)(h * NCH + c) * 4096;   // [p][s]
    rg = Ccb; obase = h * 64; ostride = DI;
  }
  for (int gi = tid; gi < 4096; gi += 256)
    S0l[(gi & 63) * 68 + (gi >> 6)] = s0g[gi];
  {
    int t = tid >> 3, q = (tid & 7) * 8;
    const float4* src = (const float4*)&rg[(size_t)(t0 + t) * ostride + obase + q];
    float4* dst = (float4*)&Rl[t * 68 + q];
    dst[0] = src[0]; dst[1] = src[1];
  }
  __syncthreads();
  int t = tid >> 3, q = (tid & 7) * 8;
  float acc[8];
#pragma unroll
  for (int j = 0; j < 8; j++) acc[j] = 0.f;
  for (int k = 0; k < 64; ++k) {
    float rv = Rl[t * 68 + k];
    const float4* sp = (const float4*)&S0l[k * 68 + q];
    float4 s0 = sp[0], s1 = sp[1];
    acc[0] = fmaf(rv, s0.x, acc[0]);
    acc[1] = fmaf(rv, s0.y, acc[1]);
    acc[2] = fmaf(rv, s0.z, acc[2]);
    acc[3] = fmaf(rv, s0.w, acc[3]);
    acc[4] = fmaf(rv, s1.x, acc[4]);
    acc[5] = fmaf(rv, s1.y, acc[5]);
    acc[6] = fmaf(rv, s1.z, acc[6]);
    acc[7] = fmaf(rv, s1.w, acc[7]);
  }
  if (!rwkv) {
    float4* op = (float4*)&yb[(size_t)(t0 + t) * DI + obase + q];
    float4 c0 = op[0], c1 = op[1];
    c0.x += acc[0]; c0.y += acc[1]; c0.z += acc[2]; c0.w += acc[3];
    c1.x += acc[4]; c1.y += acc[5]; c1.z += acc[6]; c1.w += acc[7];
    op[0] = c0; op[1] = c1;
  } else {
    float ov[8];
    const float4* sp = (const float4*)&so[(size_t)(t0 + t) * DD + obase + q];
    float4 s0 = sp[0], s1 = sp[1];
    ov[0] = s0.x + acc[0]; ov[1] = s0.y + acc[1]; ov[2] = s0.z + acc[2]; ov[3] = s0.w + acc[3];
    ov[4] = s1.x + acc[4]; ov[5] = s1.y + acc[5]; ov[6] = s1.z + acc[6]; ov[7] = s1.w + acc[7];
    float m_ = 0.f;
#pragma unroll
    for (int j = 0; j < 8; j++) m_ += ov[j];
    m_ += __shfl_xor(m_, 1); m_ += __shfl_xor(m_, 2); m_ += __shfl_xor(m_, 4);
    float mu = m_ * (1.f / 64.f);
    float vv = 0.f;
#pragma unroll
    for (int j = 0; j < 8; j++) { float d = ov[j] - mu; vv = fmaf(d, d, vv); }
    vv += __shfl_xor(vv, 1); vv += __shfl_xor(vv, 2); vv += __shfl_xor(vv, 4);
    float rstd = rsqrtf(vv * (1.f / 64.f) + 1e-5f);
#pragma unroll
    for (int j = 0; j < 8; j++) {
      int d = obase + q + j;
      float gv = PZ[(size_t)(t0 + t) * PZS + G_OFF + d];
      float o = fmaf((ov[j] - mu) * rstd, gnw[d], gnb[d]) * siluf(gv);
      gob[(size_t)(t0 + t) * DD + d] = f2b(o);
    }
  }
}

// ---------------- Mamba out: rms(y * silu(z), mn_w) -> bf16 (wave per row) ----------------
__global__ __launch_bounds__(256) void mamba_norm_kernel(const float* __restrict__ yb,
    const float* __restrict__ PZ, const float* __restrict__ mnw, unsigned short* __restrict__ out)
{
  int row = blockIdx.x * 4 + (threadIdx.x >> 6);
  int lane = threadIdx.x & 63;
  float v[12]; float ss = 0.f;
#pragma unroll
  for (int j = 0; j < 12; ++j) {
    int c = lane + j * 64;
    float z = PZ[(size_t)row * PZS + Z_OFF + c];
    float t = yb[(size_t)row * DI + c] * siluf(z);
    v[j] = t; ss = fmaf(t, t, ss);
  }
#pragma unroll
  for (int s = 1; s < 64; s <<= 1) ss += __shfl_xor(ss, s);
  float scale = rsqrtf(ss * (1.f / DI) + 1e-6f);
#pragma unroll
  for (int j = 0; j < 12; ++j) {
    int c = lane + j * 64;
    out[(size_t)row * DI + c] = f2b(v[j] * scale * mnw[c]);
  }
}

// ---------------- gate combine + FFN RMSNorm (wave per row) ----------------
__global__ __launch_bounds__(256) void gate_rms_kernel(const float* __restrict__ orb,
    const float* __restrict__ omb, const float* __restrict__ gw,
    const float* __restrict__ gb, const float* __restrict__ flnw,
    float* __restrict__ h, unsigned short* __restrict__ xnb)
{
  int row = blockIdx.x * 4 + (threadIdx.x >> 6);
  int lane = threadIdx.x & 63;
  float a[6], bq[6]; float ss = 0.f;
#pragma unroll
  for (int j = 0; j < 6; ++j) {
    int c = lane + j * 64;
    a[j] = orb[(size_t)row * DD + c]; bq[j] = omb[(size_t)row * DD + c];
    ss += a[j] * gw[c] + bq[j] * gw[DD + c];
  }
#pragma unroll
  for (int s = 1; s < 64; s <<= 1) ss += __shfl_xor(ss, s);
  float gate = sigmoidf_(ss + gb[0]);
  float hn[6]; float ss2 = 0.f;
#pragma unroll
  for (int j = 0; j < 6; ++j) {
    int c = lane + j * 64;
    size_t ix = (size_t)row * DD + c;
    hn[j] = h[ix] + gate * a[j] + (1.f - gate) * bq[j];
    h[ix] = hn[j];
    ss2 = fmaf(hn[j], hn[j], ss2);
  }
#pragma unroll
  for (int s = 1; s < 64; s <<= 1) ss2 += __shfl_xor(ss2, s);
  float scale = rsqrtf(ss2 * (1.f / DD) + 1e-6f);
#pragma unroll
  for (int j = 0; j < 6; ++j) {
    int c = lane + j * 64;
    xnb[(size_t)row * DD + c] = f2b(flnw[c] * hn[j] * scale);
  }
}

// ---------------- launcher ----------------
extern "C" void kernel_launch(void* const* d_in, const int* in_sizes, int n_in,
                              void* d_out, int out_size, void* d_ws, size_t ws_size,
                              hipStream_t stream)
{
  const int*   x        = (const int*)  d_in[0];
  const float* embed    = (const float*)d_in[1];
  const float* ln_w     = (const float*)d_in[2];
  const float* Wr       = (const float*)d_in[3];
  const float* Wk       = (const float*)d_in[4];
  const float* Wv       = (const float*)d_in[5];
  const float* Wg       = (const float*)d_in[6];
  const float* Ww       = (const float*)d_in[7];
  const float* w_bias   = (const float*)d_in[8];
  const float* u        = (const float*)d_in[9];
  const float* gn_w     = (const float*)d_in[10];
  const float* gn_b     = (const float*)d_in[11];
  const float* Wo       = (const float*)d_in[12];
  const float* W_in     = (const float*)d_in[13];
  const float* conv_w   = (const float*)d_in[14];
  const float* conv_b   = (const float*)d_in[15];
  const float* dt_bias  = (const float*)d_in[16];
  const float* A_log    = (const float*)d_in[17];
  const float* Dp       = (const float*)d_in[18];
  const float* mn_w     = (const float*)d_in[19];
  const float* W_out    = (const float*)d_in[20];
  const float* gw       = (const float*)d_in[21];
  const float* gb       = (const float*)d_in[22];
  const float* ffn_ln_w = (const float*)d_in[23];
  const float* ffn_w1   = (const float*)d_in[24];
  const float* ffn_w2   = (const float*)d_in[25];
  const float* ln_out_w = (const float*)d_in[26];

  char* base = (char*)d_ws;
  size_t off = 0;
  auto alloc = [&](size_t bytes) { off = (off + 255) & ~(size_t)255; void* p = base + off; off += bytes; return p; };

  float* h    = (float*)alloc((size_t)TT * DD * 4);
  float* PZ   = (float*)alloc((size_t)TT * PZS * 4);
  float* yb   = (float*)alloc((size_t)TT * DI * 4);
  float* so   = (float*)alloc((size_t)TT * DD * 4);
  float* orb  = (float*)alloc((size_t)TT * DD * 4);
  float* omb  = (float*)alloc((size_t)TT * DD * 4);
  float* rPb  = (float*)alloc((size_t)TT * DD * 4);
  float* Ccb  = (float*)alloc((size_t)TT * DI * 4);
  float* MstR = (float*)alloc((size_t)NH * NCH * 4096 * 4);
  float* DcR  = (float*)alloc((size_t)NH * NCH * 64 * 4);
  float* S0R  = (float*)alloc((size_t)NH * NCH * 4096 * 4);
  float* MstM = (float*)alloc((size_t)MH * NCH * 4096 * 4);
  float* DcM  = (float*)alloc((size_t)MH * NCH * 4);
  float* S0M  = (float*)alloc((size_t)MH * NCH * 4096 * 4);
  unsigned short* xnb = (unsigned short*)alloc((size_t)TT * DD * 2);
  unsigned short* gob = (unsigned short*)alloc((size_t)TT * DD * 2);
  unsigned short* ynb = (unsigned short*)alloc((size_t)TT * DI * 2);
  unsigned short* fhb = (unsigned short*)alloc((size_t)TT * 1536 * 2);
  unsigned short* WallT = (unsigned short*)alloc((size_t)NL * PZS * 384 * 2);
  unsigned short* WoT   = (unsigned short*)alloc((size_t)NL * 384 * 384 * 2);
  unsigned short* WoutT = (unsigned short*)alloc((size_t)NL * 384 * 768 * 2);
  unsigned short* F1T   = (unsigned short*)alloc((size_t)NL * 1536 * 384 * 2);
  unsigned short* F2T   = (unsigned short*)alloc((size_t)NL * 384 * 1536 * 2);
  unsigned short* embB  = (unsigned short*)alloc((size_t)NV * DD * 2);
  (void)ws_size; (void)in_sizes; (void)n_in; (void)out_size;

  dim3 blk(256);
  int gTD = (TT * DD + 255) / 256;

  // ---- one-time (per launch) weight conversion: WallT rows [r|k|v|g|w|z..] ----
  const float* Wrkvgw[5] = {Wr, Wk, Wv, Wg, Ww};
  for (int j = 0; j < 5; ++j)
    transconv_kernel<<<dim3(12, 12, 8), blk, 0, stream>>>(
        Wrkvgw[j], WallT + (size_t)j * 384 * 384, 384, 384, 384,
        (size_t)384 * 384, (size_t)PZS * 384);
  transconv_kernel<<<dim3(56, 12, 8), blk, 0, stream>>>(
      W_in, WallT + (size_t)1920 * 384, 384, XDIM, 1792,
      (size_t)384 * XDIM, (size_t)PZS * 384);
  transconv_kernel<<<dim3(12, 12, 8), blk, 0, stream>>>(
      Wo, WoT, 384, 384, 384, (size_t)384 * 384, (size_t)384 * 384);
  transconv_kernel<<<dim3(12, 24, 8), blk, 0, stream>>>(
      W_out, WoutT, 768, 384, 384, (size_t)768 * 384, (size_t)384 * 768);
  transconv_kernel<<<dim3(48, 12, 8), blk, 0, stream>>>(
      ffn_w1, F1T, 384, 1536, 1536, (size_t)384 * 1536, (size_t)1536 * 384);
  transconv_kernel<<<dim3(12, 48, 8), blk, 0, stream>>>(
      ffn_w2, F2T, 1536, 384, 384, (size_t)1536 * 384, (size_t)384 * 1536);
  conv_b16_kernel<<<(NV * DD + 255) / 256, blk, 0, stream>>>(embed, embB, NV * DD);

  embed_kernel<<<gTD, blk, 0, stream>>>(x, embed, h);

  for (int i = 0; i < NL; ++i) {
    rms_kernel<<<256, blk, 0, stream>>>(h, ln_w + (size_t)i * DD, xnb);

    gemm_bf16<0><<<dim3(58, 16), blk, 0, stream>>>(
        xnb, WallT + (size_t)i * PZS * 384, PZ, nullptr, PZS, 384, PZS);

    scanA_kernel<<<576, blk, 0, stream>>>(PZ, u + (size_t)i * NH * 64, w_bias + (size_t)i * DD,
                                          so, rPb, MstR, DcR,
                                          conv_w + (size_t)i * CONVC * 4, conv_b + (size_t)i * CONVC,
                                          dt_bias + (size_t)i * MH,
                                          A_log + (size_t)i * MH, Dp + (size_t)i * MH,
                                          yb, Ccb, MstM, DcM);
    combine_kernel<<<288, blk, 0, stream>>>(MstR, DcR, S0R, MstM, DcM, S0M);
    corr_kernel<<<576, blk, 0, stream>>>(S0R, rPb, so, S0M, Ccb, yb,
                                         PZ, gn_w + (size_t)i * DD, gn_b + (size_t)i * DD, gob);

    mamba_norm_kernel<<<256, blk, 0, stream>>>(yb, PZ, mn_w + (size_t)i * DI, ynb);

    gemm_dual<<<192, blk, 0, stream>>>(
        gob, WoT + (size_t)i * 384 * 384, orb, 384, DD, 6, 96,
        ynb, WoutT + (size_t)i * 384 * 768, omb, 768, DD, 6);

    gate_rms_kernel<<<256, blk, 0, stream>>>(orb, omb, gw + (size_t)i * 2 * DD, gb + i,
                                             ffn_ln_w + (size_t)i * DD, h, xnb);

    gemm_bf16<1><<<dim3(24, 16), blk, 0, stream>>>(
        xnb, F1T + (size_t)i * 1536 * 384, nullptr, fhb, 1536, 384, 1536);
    gemm_bf16<3><<<dim3(6, 16, 4), blk, 0, stream>>>(
        fhb, F2T + (size_t)i * 384 * 1536, h, nullptr, DD, 1536, DD);
  }

  rms_kernel<<<256, blk, 0, stream>>>(h, ln_out_w, xnb);
  gemm128<<<dim3(250, 8), blk, 0, stream>>>(
      xnb, embB, (float*)d_out, NV, 384, NV);
}